// Round 1
// baseline (1721.596 us; speedup 1.0000x reference)
//
#include <hip/hip_runtime.h>
#include <math.h>

// Problem constants
#define NN 150   // nodes
#define BB 32    // batch
#define TT 8     // time
#define FF 16    // input features
#define HH 32    // hidden
#define ROWS (NN*BB)     // 4800 (row index = n*32 + b)
#define NCIN (BB*FF)     // 512
#define NCH  (BB*HH)     // 1024

// workspace sizes (floats)
#define SZ_ADJF (4*NN*NN)
#define SZ_WA0  (4*48*96)
#define SZ_WA1  (4*64*96)
#define SZ_WB   (4*32*32)
#define SZ_STATE (ROWS*HH*4)
#define SZ_PIN  (4*NN*NCIN)

__device__ __forceinline__ float sigmoidf_(float x){ return 1.f/(1.f+expf(-x)); }

// Fourier comps of a real length-4 tube: c0, c1re, c1im, c2 (face3 = conj(face1))
// ifft: y0=(c0+2c1re+c2)/4; y1=(c0-2c1im-c2)/4; y2=(c0-2c1re+c2)/4; y3=(c0+2c1im-c2)/4

// ---------------- adjacency: softmax(relu(ifft(Uf Uf^T))) then comps ----------------
__global__ __launch_bounds__(256) void k_adj(const float* __restrict__ U, float* __restrict__ adjF) {
  __shared__ float Ufl[NN*16*4];
  __shared__ float Arow[NN*4];
  __shared__ float red[256];
  __shared__ float mxs[4], isms[4];
  int n = blockIdx.x, tid = threadIdx.x;
  for (int idx = tid; idx < NN*16; idx += 256) {
    const float* s = U + (size_t)idx*4;
    float x0=s[0], x1=s[1], x2=s[2], x3=s[3];
    Ufl[idx*4+0] = x0+x1+x2+x3;
    Ufl[idx*4+1] = x0-x2;
    Ufl[idx*4+2] = x3-x1;
    Ufl[idx*4+3] = x0-x1+x2-x3;
  }
  __syncthreads();
  if (tid < NN) {
    int m = tid;
    float a0=0, ar=0, ai=0, a2=0;
    #pragma unroll
    for (int e = 0; e < 16; ++e) {
      const float* un = &Ufl[(n*16+e)*4];
      const float* um = &Ufl[(m*16+e)*4];
      a0 += un[0]*um[0];
      ar += un[1]*um[1] - un[2]*um[2];
      ai += un[1]*um[2] + un[2]*um[1];
      a2 += un[3]*um[3];
    }
    float r0 = 0.25f*(a0 + 2.f*ar + a2);
    float r1 = 0.25f*(a0 - 2.f*ai - a2);
    float r2 = 0.25f*(a0 - 2.f*ar + a2);
    float r3 = 0.25f*(a0 + 2.f*ai - a2);
    Arow[m*4+0] = fmaxf(r0, 0.f);
    Arow[m*4+1] = fmaxf(r1, 0.f);
    Arow[m*4+2] = fmaxf(r2, 0.f);
    Arow[m*4+3] = fmaxf(r3, 0.f);
  }
  __syncthreads();
  for (int r = 0; r < 4; ++r) {
    float v = (tid < NN) ? Arow[tid*4+r] : -1e30f;
    red[tid] = v; __syncthreads();
    for (int s = 128; s > 0; s >>= 1) { if (tid < s) red[tid] = fmaxf(red[tid], red[tid+s]); __syncthreads(); }
    if (tid == 0) mxs[r] = red[0];
    __syncthreads();
    float e = (tid < NN) ? expf(Arow[tid*4+r] - mxs[r]) : 0.f;
    red[tid] = e; __syncthreads();
    for (int s = 128; s > 0; s >>= 1) { if (tid < s) red[tid] += red[tid+s]; __syncthreads(); }
    if (tid == 0) isms[r] = 1.f / red[0];
    __syncthreads();
    if (tid < NN) Arow[tid*4+r] = e * isms[r];
    __syncthreads();
  }
  if (tid < NN) {
    int m = tid;
    float e0=Arow[m*4+0], e1=Arow[m*4+1], e2=Arow[m*4+2], e3=Arow[m*4+3];
    size_t base = (size_t)n*NN + m;
    size_t cs = (size_t)NN*NN;
    adjF[base]      = e0+e1+e2+e3;
    adjF[base+cs]   = e0-e2;
    adjF[base+2*cs] = e3-e1;
    adjF[base+3*cs] = e0-e1+e2-e3;
  }
}

// ---------------- build GEMM-ready weight comps ----------------
// WA0 [4][48][96]: rows 0..15 = Wxz0|Wxr0|Wxh0 ; rows 16..47 = Whz0|Whr0|0
// WA1 [4][64][96]: rows 0..31 = Wx*1 ; rows 32..63 = Whz1|Whr1|0
// WB0/WB1 [4][32][32] = comps of Whr0/Whr1
__global__ __launch_bounds__(256) void k_wts(
    const float* __restrict__ Wxz0, const float* __restrict__ Wxr0, const float* __restrict__ Wxh0,
    const float* __restrict__ Whz0, const float* __restrict__ Whr0,
    const float* __restrict__ Wxz1, const float* __restrict__ Wxr1, const float* __restrict__ Wxh1,
    const float* __restrict__ Whz1, const float* __restrict__ Whr1,
    float* __restrict__ WA0, float* __restrict__ WA1, float* __restrict__ WB0, float* __restrict__ WB1) {
  int idx = blockIdx.x*256 + threadIdx.x;
  const float* src = nullptr;
  float* dst; int didx; int c;
  if (idx < 4*48*96) {
    c = idx / (48*96);
    int rem = idx % (48*96);
    int k = rem / 96, o = rem % 96;
    int gate = o / 32, oc = o & 31;
    if (k < FF) src = (gate==0 ? Wxz0 : gate==1 ? Wxr0 : Wxh0) + ((size_t)k*HH + oc)*4;
    else if (gate < 2) src = (gate==0 ? Whz0 : Whr0) + ((size_t)(k-FF)*HH + oc)*4;
    dst = WA0; didx = idx;
  } else if (idx < 4*48*96 + 4*64*96) {
    int id2 = idx - 4*48*96;
    c = id2 / (64*96);
    int rem = id2 % (64*96);
    int k = rem / 96, o = rem % 96;
    int gate = o / 32, oc = o & 31;
    if (k < HH) src = (gate==0 ? Wxz1 : gate==1 ? Wxr1 : Wxh1) + ((size_t)k*HH + oc)*4;
    else if (gate < 2) src = (gate==0 ? Whz1 : Whr1) + ((size_t)(k-HH)*HH + oc)*4;
    dst = WA1; didx = id2;
  } else if (idx < 4*48*96 + 4*64*96 + 4096) {
    int id3 = idx - (4*48*96 + 4*64*96);
    c = id3 >> 10;
    int k = (id3 >> 5) & 31, o = id3 & 31;
    src = Whr0 + ((size_t)k*HH + o)*4;
    dst = WB0; didx = id3;
  } else if (idx < 4*48*96 + 4*64*96 + 8192) {
    int id4 = idx - (4*48*96 + 4*64*96 + 4096);
    c = id4 >> 10;
    int k = (id4 >> 5) & 31, o = id4 & 31;
    src = Whr1 + ((size_t)k*HH + o)*4;
    dst = WB1; didx = id4;
  } else return;
  float v0=0,v1=0,v2=0,v3=0;
  if (src) { v0=src[0]; v1=src[1]; v2=src[2]; v3=src[3]; }
  float comp = (c==0) ? (v0+v1+v2+v3) : (c==1) ? (v0-v2) : (c==2) ? (v3-v1) : (v0-v1+v2-v3);
  dst[didx] = comp;
}

// ---------------- facewise aggregation: P[c][n][col] = (Af . X)[c] ----------------
// comps: P0=A0*X0 ; P1re=A1r*X1r-A1i*X1i ; P1im=A1r*X1i+A1i*X1r ; P2=A2*X2
struct AggParams {
  const float* X0; const float* X1; const float* X2;
  float* P0; float* P1; float* P2;
  int ncol0, ncol1, ncol2;
  int base1, base2, njobs, rawt;   // rawt>=0: job0 reads raw inputs at time t (computes comps on the fly)
};
__global__ __launch_bounds__(256) void k_agg(AggParams pr, const float* __restrict__ adjF,
                                             const float* __restrict__ inp) {
  __shared__ float As[4*32*36];   // [c][k][row], row stride 36 (16B aligned, few conflicts)
  __shared__ float Xs[4*32*64];   // [c][k][col]
  int bid = blockIdx.x;
  const float* X; float* P; int ncol; int tile; bool raw = false;
  if (pr.njobs >= 3 && bid >= pr.base2) { X = pr.X2; P = pr.P2; ncol = pr.ncol2; tile = bid - pr.base2; }
  else if (pr.njobs >= 2 && bid >= pr.base1) { X = pr.X1; P = pr.P1; ncol = pr.ncol1; tile = bid - pr.base1; }
  else { X = pr.X0; P = pr.P0; ncol = pr.ncol0; tile = bid; raw = (pr.rawt >= 0); }
  int n0 = (tile % 5) * 32;
  int col0 = (tile / 5) * 64;
  int tid = threadIdx.x;
  int tx = tid & 31, ty = tid >> 5;
  int i0 = ty * 4, j0 = tx * 2;
  float acc0[4][2] = {}; float accR[4][2] = {}; float accI[4][2] = {}; float acc2[4][2] = {};
  for (int k0 = 0; k0 < NN; k0 += 32) {
    __syncthreads();
    // A tile: As[c][kk][i] = adjF[c][n0+i][k0+kk]
    #pragma unroll
    for (int u = 0; u < 16; ++u) {
      int e = tid + u * 256;
      int c = e >> 10, rem = e & 1023, i = rem >> 5, kk = rem & 31;
      int nn_ = n0 + i, mm = k0 + kk;
      float v = 0.f;
      if (nn_ < NN && mm < NN) v = adjF[((size_t)c * NN + nn_) * NN + mm];
      As[(c*32 + kk)*36 + i] = v;
    }
    if (raw) {
      // read raw inputs [b][t][m][f][r], compute comps on the fly
      #pragma unroll
      for (int u = 0; u < 2; ++u) {
        int g = tid + u*256;             // 512 groups: [kk][q]
        int q = g & 15, kk = g >> 4;
        int mm = k0 + kk;
        int col = col0 + q*4;
        int b = col >> 4, f = col & 15;  // 4 consecutive f for same b
        float4 r0 = make_float4(0,0,0,0), r1 = r0, r2 = r0, r3 = r0;
        if (mm < NN) {
          const float* s = inp + (((size_t)(b*TT + pr.rawt)*NN + mm)*FF + f)*4;
          r0 = *(const float4*)(s+0);
          r1 = *(const float4*)(s+4);
          r2 = *(const float4*)(s+8);
          r3 = *(const float4*)(s+12);
        }
        float4 w;
        w = make_float4(r0.x+r0.y+r0.z+r0.w, r1.x+r1.y+r1.z+r1.w, r2.x+r2.y+r2.z+r2.w, r3.x+r3.y+r3.z+r3.w);
        *(float4*)&Xs[(0*32+kk)*64 + q*4] = w;
        w = make_float4(r0.x-r0.z, r1.x-r1.z, r2.x-r2.z, r3.x-r3.z);
        *(float4*)&Xs[(1*32+kk)*64 + q*4] = w;
        w = make_float4(r0.w-r0.y, r1.w-r1.y, r2.w-r2.y, r3.w-r3.y);
        *(float4*)&Xs[(2*32+kk)*64 + q*4] = w;
        w = make_float4(r0.x-r0.y+r0.z-r0.w, r1.x-r1.y+r1.z-r1.w, r2.x-r2.y+r2.z-r2.w, r3.x-r3.y+r3.z-r3.w);
        *(float4*)&Xs[(3*32+kk)*64 + q*4] = w;
      }
    } else {
      #pragma unroll
      for (int u = 0; u < 8; ++u) {
        int e = tid + u*256;             // 2048 float4s
        int c = e >> 9, rem = e & 511, kk = rem >> 4, q = rem & 15;
        int mm = k0 + kk;
        float4 v = make_float4(0,0,0,0);
        if (mm < NN) v = *(const float4*)(X + ((size_t)c*NN + mm)*ncol + col0 + q*4);
        *(float4*)&Xs[(c*32+kk)*64 + q*4] = v;
      }
    }
    __syncthreads();
    #pragma unroll 4
    for (int k = 0; k < 32; ++k) {
      float4 a0 = *(float4*)&As[(0*32+k)*36 + i0];
      float4 a1 = *(float4*)&As[(1*32+k)*36 + i0];
      float4 a2 = *(float4*)&As[(2*32+k)*36 + i0];
      float4 a3 = *(float4*)&As[(3*32+k)*36 + i0];
      float2 x0 = *(float2*)&Xs[(0*32+k)*64 + j0];
      float2 x1 = *(float2*)&Xs[(1*32+k)*64 + j0];
      float2 x2 = *(float2*)&Xs[(2*32+k)*64 + j0];
      float2 x3 = *(float2*)&Xs[(3*32+k)*64 + j0];
      float A0v[4]={a0.x,a0.y,a0.z,a0.w}, A1v[4]={a1.x,a1.y,a1.z,a1.w};
      float A2v[4]={a2.x,a2.y,a2.z,a2.w}, A3v[4]={a3.x,a3.y,a3.z,a3.w};
      float X0v[2]={x0.x,x0.y}, X1v[2]={x1.x,x1.y}, X2v[2]={x2.x,x2.y}, X3v[2]={x3.x,x3.y};
      #pragma unroll
      for (int i = 0; i < 4; ++i) {
        #pragma unroll
        for (int j = 0; j < 2; ++j) {
          acc0[i][j] += A0v[i]*X0v[j];
          accR[i][j] += A1v[i]*X1v[j] - A2v[i]*X2v[j];
          accI[i][j] += A1v[i]*X2v[j] + A2v[i]*X1v[j];
          acc2[i][j] += A3v[i]*X3v[j];
        }
      }
    }
  }
  size_t cs = (size_t)NN*ncol;
  #pragma unroll
  for (int i = 0; i < 4; ++i) {
    int nn_ = n0 + i0 + i;
    if (nn_ >= NN) continue;
    size_t rb = (size_t)nn_*ncol + col0 + j0;
    *(float2*)&P[rb]      = make_float2(acc0[i][0], acc0[i][1]);
    *(float2*)&P[rb+cs]   = make_float2(accR[i][0], accR[i][1]);
    *(float2*)&P[rb+2*cs] = make_float2(accI[i][0], accI[i][1]);
    *(float2*)&P[rb+3*cs] = make_float2(acc2[i][0], acc2[i][1]);
  }
}

// ---------------- phase A: transform + gates -> Z, T1(=h-part+bh), Mf(comps of Rg*Hprev) ----------------
struct FAJob {
  const float* Px;   // [c][ROWS][Kx]
  const float* Ph;   // [c][ROWS][32]
  const float* W;    // [c][Ktot][96]
  const float* bias; // raw B ptr [3][32][4]
  const float* hprev;// [ROWS][32][4]
  float* Z; float* T1; float* Mf;
  int Kx, Ktot, zh;
};
struct FAParams { FAJob j[2]; };
__global__ __launch_bounds__(256) void k_fusedA(FAParams pr) {
  __shared__ float Ps[4*32*65];   // [c][row][k], stride 65
  __shared__ float Ws[4*16*96];   // [c][k16][o]
  FAJob jb = pr.j[blockIdx.y];
  int Ktot = jb.Ktot, Kx = jb.Kx;
  int row0 = blockIdx.x * 32;
  int tid = threadIdx.x;
  int rl = tid >> 3, og = tid & 7, o0 = og * 12;
  int tot = 4 * 32 * Ktot;
  for (int e = tid; e < tot; e += 256) {
    int k = e % Ktot; int rem = e / Ktot; int r = rem & 31; int c = rem >> 5;
    float v;
    if (k < Kx) v = jb.Px[((size_t)c*ROWS + row0 + r)*Kx + k];
    else        v = jb.zh ? 0.f : jb.Ph[((size_t)c*ROWS + row0 + r)*HH + (k-Kx)];
    Ps[(c*32 + r)*65 + k] = v;
  }
  float acc0[12]={}, accR[12]={}, accI[12]={}, acc2[12]={};
  int nch = Ktot >> 4;
  for (int cc = 0; cc < nch; ++cc) {
    __syncthreads();
    for (int e = tid; e < 6144; e += 256) {
      int o = e % 96; int rem = e / 96; int k = rem & 15; int c = rem >> 4;
      Ws[(c*16 + k)*96 + o] = jb.W[((size_t)c*Ktot + cc*16 + k)*96 + o];
    }
    __syncthreads();
    #pragma unroll 2
    for (int k = 0; k < 16; ++k) {
      int kk = cc*16 + k;
      float p0 = Ps[(0*32+rl)*65 + kk];
      float p1 = Ps[(1*32+rl)*65 + kk];
      float p2 = Ps[(2*32+rl)*65 + kk];
      float p3 = Ps[(3*32+rl)*65 + kk];
      #pragma unroll
      for (int q = 0; q < 3; ++q) {
        float4 w0 = *(float4*)&Ws[(0*16+k)*96 + o0 + q*4];
        float4 w1 = *(float4*)&Ws[(1*16+k)*96 + o0 + q*4];
        float4 w2 = *(float4*)&Ws[(2*16+k)*96 + o0 + q*4];
        float4 w3 = *(float4*)&Ws[(3*16+k)*96 + o0 + q*4];
        float W0v[4]={w0.x,w0.y,w0.z,w0.w}, W1v[4]={w1.x,w1.y,w1.z,w1.w};
        float W2v[4]={w2.x,w2.y,w2.z,w2.w}, W3v[4]={w3.x,w3.y,w3.z,w3.w};
        #pragma unroll
        for (int s = 0; s < 4; ++s) {
          int jj = q*4 + s;
          acc0[jj] += p0*W0v[s];
          accR[jj] += p1*W1v[s] - p2*W2v[s];
          accI[jj] += p1*W2v[s] + p2*W1v[s];
          acc2[jj] += p3*W3v[s];
        }
      }
    }
  }
  int row = row0 + rl;
  #pragma unroll
  for (int jj = 0; jj < 12; ++jj) {
    int o = o0 + jj;
    float Y0 = acc0[jj], Yr = accR[jj], Yi = accI[jj], Y2 = acc2[jj];
    float y0 = 0.25f*(Y0 + 2.f*Yr + Y2);
    float y1 = 0.25f*(Y0 - 2.f*Yi - Y2);
    float y2 = 0.25f*(Y0 - 2.f*Yr + Y2);
    float y3 = 0.25f*(Y0 + 2.f*Yi - Y2);
    if (o < HH) {
      const float* bz = jb.bias + (0*HH + o)*4;
      float4 z = make_float4(sigmoidf_(y0+bz[0]), sigmoidf_(y1+bz[1]),
                             sigmoidf_(y2+bz[2]), sigmoidf_(y3+bz[3]));
      *(float4*)&jb.Z[((size_t)row*HH + o)*4] = z;
    } else if (o < 2*HH) {
      int oc = o - HH;
      const float* br = jb.bias + (1*HH + oc)*4;
      float4 hp = make_float4(0,0,0,0);
      if (!jb.zh) hp = *(const float4*)&jb.hprev[((size_t)row*HH + oc)*4];
      float m0 = sigmoidf_(y0+br[0]) * hp.x;
      float m1 = sigmoidf_(y1+br[1]) * hp.y;
      float m2 = sigmoidf_(y2+br[2]) * hp.z;
      float m3 = sigmoidf_(y3+br[3]) * hp.w;
      size_t mb = (size_t)row*HH + oc;
      size_t cs = (size_t)ROWS*HH;
      jb.Mf[mb]      = m0+m1+m2+m3;
      jb.Mf[mb+cs]   = m0-m2;
      jb.Mf[mb+2*cs] = m3-m1;
      jb.Mf[mb+3*cs] = m0-m1+m2-m3;
    } else {
      int oc = o - 2*HH;
      const float* bh = jb.bias + (2*HH + oc)*4;
      float4 tv = make_float4(y0+bh[0], y1+bh[1], y2+bh[2], y3+bh[3]);
      *(float4*)&jb.T1[((size_t)row*HH + oc)*4] = tv;
    }
  }
}

// ---------------- phase B: Ht=tanh(T1+ifft(Pm.W)); Hnew=Z*Hprev+(1-Z)*Ht; emit h, hf comps, out ----------------
struct FBJob {
  const float* Pm; const float* W; const float* T1; const float* Z;
  float* h; float* hf; float* outp;
  int t, zh, wout;
};
struct FBParams { FBJob j[2]; };
__global__ __launch_bounds__(256) void k_fusedB(FBParams pr) {
  __shared__ float Ps[4*32*33];
  __shared__ float Ws[4*32*32];
  FBJob jb = pr.j[blockIdx.y];
  int row0 = blockIdx.x * 32;
  int tid = threadIdx.x;
  int rl = tid >> 3, og = tid & 7, o0 = og * 4;
  float acc0[4]={}, accR[4]={}, accI[4]={}, acc2[4]={};
  if (!jb.zh) {
    for (int e = tid; e < 4096; e += 256) {
      int k = e & 31, r = (e >> 5) & 31, c = e >> 10;
      Ps[(c*32 + r)*33 + k] = jb.Pm[((size_t)c*ROWS + row0 + r)*HH + k];
    }
    for (int e = tid; e < 4096; e += 256) Ws[e] = jb.W[e];
    __syncthreads();
    #pragma unroll 4
    for (int k = 0; k < 32; ++k) {
      float p0 = Ps[(0*32+rl)*33 + k];
      float p1 = Ps[(1*32+rl)*33 + k];
      float p2 = Ps[(2*32+rl)*33 + k];
      float p3 = Ps[(3*32+rl)*33 + k];
      float4 w0 = *(float4*)&Ws[(0*32+k)*32 + o0];
      float4 w1 = *(float4*)&Ws[(1*32+k)*32 + o0];
      float4 w2 = *(float4*)&Ws[(2*32+k)*32 + o0];
      float4 w3 = *(float4*)&Ws[(3*32+k)*32 + o0];
      float W0v[4]={w0.x,w0.y,w0.z,w0.w}, W1v[4]={w1.x,w1.y,w1.z,w1.w};
      float W2v[4]={w2.x,w2.y,w2.z,w2.w}, W3v[4]={w3.x,w3.y,w3.z,w3.w};
      #pragma unroll
      for (int s = 0; s < 4; ++s) {
        acc0[s] += p0*W0v[s];
        accR[s] += p1*W1v[s] - p2*W2v[s];
        accI[s] += p1*W2v[s] + p2*W1v[s];
        acc2[s] += p3*W3v[s];
      }
    }
  }
  int row = row0 + rl, n = row >> 5, b = row & 31;
  #pragma unroll
  for (int s = 0; s < 4; ++s) {
    int o = o0 + s;
    float Y0 = acc0[s], Yr = accR[s], Yi = accI[s], Y2 = acc2[s];
    float y0 = 0.25f*(Y0 + 2.f*Yr + Y2);
    float y1 = 0.25f*(Y0 - 2.f*Yi - Y2);
    float y2 = 0.25f*(Y0 - 2.f*Yr + Y2);
    float y3 = 0.25f*(Y0 + 2.f*Yi - Y2);
    float4 t1 = *(const float4*)&jb.T1[((size_t)row*HH + o)*4];
    float h0v = tanhf(t1.x + y0);
    float h1v = tanhf(t1.y + y1);
    float h2v = tanhf(t1.z + y2);
    float h3v = tanhf(t1.w + y3);
    float4 z = *(const float4*)&jb.Z[((size_t)row*HH + o)*4];
    float4 hp = make_float4(0,0,0,0);
    if (!jb.zh) hp = *(const float4*)&jb.h[((size_t)row*HH + o)*4];
    float n0v = z.x*hp.x + (1.f-z.x)*h0v;
    float n1v = z.y*hp.y + (1.f-z.y)*h1v;
    float n2v = z.z*hp.z + (1.f-z.z)*h2v;
    float n3v = z.w*hp.w + (1.f-z.w)*h3v;
    *(float4*)&jb.h[((size_t)row*HH + o)*4] = make_float4(n0v,n1v,n2v,n3v);
    size_t hb = (size_t)row*HH + o, cs = (size_t)ROWS*HH;
    jb.hf[hb]      = n0v+n1v+n2v+n3v;
    jb.hf[hb+cs]   = n0v-n2v;
    jb.hf[hb+2*cs] = n3v-n1v;
    jb.hf[hb+3*cs] = n0v-n1v+n2v-n3v;
    if (jb.wout) {
      float* dst = jb.outp + (((size_t)b*TT + jb.t)*NN + n)*(HH*4) + o*4;
      *(float4*)dst = make_float4(n0v,n1v,n2v,n3v);
    }
  }
}

// ---------------- h_last: [2][B][N][H][R] from h buffers [n*32+b][H][4] ----------------
__global__ __launch_bounds__(256) void k_hlast(const float* __restrict__ h0, const float* __restrict__ h1,
                                               float* __restrict__ dst) {
  int idx = blockIdx.x*256 + threadIdx.x;
  if (idx >= 2*BB*NN*HH*4) return;
  int hr = idx & 127;
  int n = (idx >> 7) % NN;
  int rest = idx / (128*NN);
  int b = rest & 31;
  int l = rest >> 5;
  const float* src = (l ? h1 : h0);
  dst[idx] = src[((size_t)(n*BB + b))*128 + hr];
}

extern "C" void kernel_launch(void* const* d_in, const int* in_sizes, int n_in,
                              void* d_out, int out_size, void* d_ws, size_t ws_size,
                              hipStream_t stream) {
  const float* inp  = (const float*)d_in[0];
  const float* U    = (const float*)d_in[1];
  const float* Wxz0 = (const float*)d_in[2];
  const float* Wxr0 = (const float*)d_in[3];
  const float* Wxh0 = (const float*)d_in[4];
  const float* Whz0 = (const float*)d_in[5];
  const float* Whr0 = (const float*)d_in[6];
  const float* B0   = (const float*)d_in[7];
  const float* Wxz1 = (const float*)d_in[8];
  const float* Wxr1 = (const float*)d_in[9];
  const float* Wxh1 = (const float*)d_in[10];
  const float* Whz1 = (const float*)d_in[11];
  const float* Whr1 = (const float*)d_in[12];
  const float* B1   = (const float*)d_in[13];
  float* out = (float*)d_out;

  float* ws = (float*)d_ws;
  float* ADJF = ws;  ws += SZ_ADJF;
  float* WA0  = ws;  ws += SZ_WA0;
  float* WA1  = ws;  ws += SZ_WA1;
  float* WB0  = ws;  ws += SZ_WB;
  float* WB1  = ws;  ws += SZ_WB;
  float* H0   = ws;  ws += SZ_STATE;
  float* H1   = ws;  ws += SZ_STATE;
  float* H0F  = ws;  ws += SZ_STATE;
  float* H1F  = ws;  ws += SZ_STATE;
  float* PIN  = ws;  ws += SZ_PIN;
  float* PH0  = ws;  ws += SZ_STATE;
  float* PH1  = ws;  ws += SZ_STATE;
  float* PM0  = ws;  ws += SZ_STATE;
  float* PM1  = ws;  ws += SZ_STATE;
  float* M0F  = ws;  ws += SZ_STATE;
  float* M1F  = ws;  ws += SZ_STATE;
  float* Z0   = ws;  ws += SZ_STATE;
  float* Z1   = ws;  ws += SZ_STATE;
  float* T10  = ws;  ws += SZ_STATE;
  float* T11  = ws;  ws += SZ_STATE;

  k_adj<<<NN, 256, 0, stream>>>(U, ADJF);
  k_wts<<<200, 256, 0, stream>>>(Wxz0,Wxr0,Wxh0,Whz0,Whr0,Wxz1,Wxr1,Wxh1,Whz1,Whr1,WA0,WA1,WB0,WB1);

  // ---- t = 0 (zero hidden) ----
  {
    AggParams p; p.X0=nullptr; p.P0=PIN; p.ncol0=NCIN;
    p.X1=nullptr; p.P1=nullptr; p.ncol1=0; p.X2=nullptr; p.P2=nullptr; p.ncol2=0;
    p.base1=0; p.base2=0; p.njobs=1; p.rawt=0;
    k_agg<<<40, 256, 0, stream>>>(p, ADJF, inp);
  }
  {
    FAParams p;
    p.j[0] = FAJob{PIN, nullptr, WA0, B0, nullptr, Z0, T10, M0F, FF, 48, 1};
    p.j[1] = p.j[0];
    k_fusedA<<<dim3(150,1), 256, 0, stream>>>(p);
  }
  {
    FBParams p;
    p.j[0] = FBJob{nullptr, WB0, T10, Z0, H0, H0F, nullptr, 0, 1, 0};
    p.j[1] = p.j[0];
    k_fusedB<<<dim3(150,1), 256, 0, stream>>>(p);
  }
  {
    AggParams p; p.X0=H0F; p.P0=PH0; p.ncol0=NCH;
    p.X1=nullptr; p.P1=nullptr; p.ncol1=0; p.X2=nullptr; p.P2=nullptr; p.ncol2=0;
    p.base1=0; p.base2=0; p.njobs=1; p.rawt=-1;
    k_agg<<<80, 256, 0, stream>>>(p, ADJF, inp);
  }
  {
    FAParams p;
    p.j[0] = FAJob{PH0, nullptr, WA1, B1, nullptr, Z1, T11, M1F, HH, 64, 1};
    p.j[1] = p.j[0];
    k_fusedA<<<dim3(150,1), 256, 0, stream>>>(p);
  }
  {
    FBParams p;
    p.j[0] = FBJob{nullptr, WB1, T11, Z1, H1, H1F, out, 0, 1, 1};
    p.j[1] = p.j[0];
    k_fusedB<<<dim3(150,1), 256, 0, stream>>>(p);
  }

  // ---- t = 1..7 ----
  for (int t = 1; t < TT; ++t) {
    {
      AggParams p;
      p.X0=nullptr; p.P0=PIN; p.ncol0=NCIN;   // raw inputs at t
      p.X1=H0F; p.P1=PH0; p.ncol1=NCH;        // agg of h0_prev (shared by L0-H and L1-X)
      p.X2=H1F; p.P2=PH1; p.ncol2=NCH;        // agg of h1_prev
      p.base1=40; p.base2=120; p.njobs=3; p.rawt=t;
      k_agg<<<200, 256, 0, stream>>>(p, ADJF, inp);
    }
    {
      FAParams p;
      p.j[0] = FAJob{PIN, PH0, WA0, B0, H0, Z0, T10, M0F, FF, 48, 0};
      p.j[1] = FAJob{PH0, PH1, WA1, B1, H1, Z1, T11, M1F, HH, 64, 0};
      k_fusedA<<<dim3(150,2), 256, 0, stream>>>(p);
    }
    {
      AggParams p;
      p.X0=M0F; p.P0=PM0; p.ncol0=NCH;
      p.X1=M1F; p.P1=PM1; p.ncol1=NCH;
      p.X2=nullptr; p.P2=nullptr; p.ncol2=0;
      p.base1=80; p.base2=0; p.njobs=2; p.rawt=-1;
      k_agg<<<160, 256, 0, stream>>>(p, ADJF, inp);
    }
    {
      FBParams p;
      p.j[0] = FBJob{PM0, WB0, T10, Z0, H0, H0F, nullptr, t, 0, 0};
      p.j[1] = FBJob{PM1, WB1, T11, Z1, H1, H1F, out, t, 0, 1};
      k_fusedB<<<dim3(150,2), 256, 0, stream>>>(p);
    }
  }
  k_hlast<<<(2*BB*NN*HH*4 + 255)/256, 256, 0, stream>>>(H0, H1, out + (size_t)BB*TT*NN*HH*4);
}

// Round 2
// 1204.218 us; speedup vs baseline: 1.4296x; 1.4296x over previous
//
#include <hip/hip_runtime.h>
#include <math.h>

// Problem constants
#define NN 150   // nodes
#define BB 32    // batch
#define TT 8     // time
#define FF 16    // input features
#define HH 32    // hidden
#define ROWS (NN*BB)     // 4800 (row index = n*32 + b)
#define NCIN (BB*FF)     // 512
#define NCH  (BB*HH)     // 1024

// workspace sizes (floats)
#define SZ_ADJF (4*NN*NN)
#define SZ_WA0  (4*48*32*4)   // packed [c][48][32][4]
#define SZ_WA1  (4*64*32*4)   // packed [c][64][32][4]
#define SZ_WB   (32*32*4)     // packed [k][o][c]
#define SZ_STATE (ROWS*HH*4)
#define SZ_PIN  (4*NN*NCIN)

__device__ __forceinline__ float sigmoidf_(float x){ return 1.f/(1.f+expf(-x)); }

__device__ __forceinline__ float comp_of4(float x0, float x1, float x2, float x3, int c) {
  return c==0 ? (x0+x1+x2+x3) : c==1 ? (x0-x2) : c==2 ? (x3-x1) : (x0-x1+x2-x3);
}

// Fourier comps of a real length-4 tube: c0, c1re, c1im, c2 (face3 = conj(face1))
// ifft: y0=(c0+2c1re+c2)/4; y1=(c0-2c1im-c2)/4; y2=(c0-2c1re+c2)/4; y3=(c0+2c1im-c2)/4

// ---------------- adjacency: softmax(relu(ifft(Uf Uf^T))) then comps ----------------
__global__ __launch_bounds__(256) void k_adj(const float* __restrict__ U, float* __restrict__ adjF) {
  __shared__ float Ufl[NN*16*4];
  __shared__ float Arow[NN*4];
  __shared__ float red[256];
  __shared__ float mxs[4], isms[4];
  int n = blockIdx.x, tid = threadIdx.x;
  for (int idx = tid; idx < NN*16; idx += 256) {
    const float* s = U + (size_t)idx*4;
    float x0=s[0], x1=s[1], x2=s[2], x3=s[3];
    Ufl[idx*4+0] = x0+x1+x2+x3;
    Ufl[idx*4+1] = x0-x2;
    Ufl[idx*4+2] = x3-x1;
    Ufl[idx*4+3] = x0-x1+x2-x3;
  }
  __syncthreads();
  if (tid < NN) {
    int m = tid;
    float a0=0, ar=0, ai=0, a2=0;
    #pragma unroll
    for (int e = 0; e < 16; ++e) {
      const float* un = &Ufl[(n*16+e)*4];
      const float* um = &Ufl[(m*16+e)*4];
      a0 += un[0]*um[0];
      ar += un[1]*um[1] - un[2]*um[2];
      ai += un[1]*um[2] + un[2]*um[1];
      a2 += un[3]*um[3];
    }
    float r0 = 0.25f*(a0 + 2.f*ar + a2);
    float r1 = 0.25f*(a0 - 2.f*ai - a2);
    float r2 = 0.25f*(a0 - 2.f*ar + a2);
    float r3 = 0.25f*(a0 + 2.f*ai - a2);
    Arow[m*4+0] = fmaxf(r0, 0.f);
    Arow[m*4+1] = fmaxf(r1, 0.f);
    Arow[m*4+2] = fmaxf(r2, 0.f);
    Arow[m*4+3] = fmaxf(r3, 0.f);
  }
  __syncthreads();
  for (int r = 0; r < 4; ++r) {
    float v = (tid < NN) ? Arow[tid*4+r] : -1e30f;
    red[tid] = v; __syncthreads();
    for (int s = 128; s > 0; s >>= 1) { if (tid < s) red[tid] = fmaxf(red[tid], red[tid+s]); __syncthreads(); }
    if (tid == 0) mxs[r] = red[0];
    __syncthreads();
    float e = (tid < NN) ? expf(Arow[tid*4+r] - mxs[r]) : 0.f;
    red[tid] = e; __syncthreads();
    for (int s = 128; s > 0; s >>= 1) { if (tid < s) red[tid] += red[tid+s]; __syncthreads(); }
    if (tid == 0) isms[r] = 1.f / red[0];
    __syncthreads();
    if (tid < NN) Arow[tid*4+r] = e * isms[r];
    __syncthreads();
  }
  if (tid < NN) {
    int m = tid;
    float e0=Arow[m*4+0], e1=Arow[m*4+1], e2=Arow[m*4+2], e3=Arow[m*4+3];
    size_t base = (size_t)n*NN + m;
    size_t cs = (size_t)NN*NN;
    adjF[base]      = e0+e1+e2+e3;
    adjF[base+cs]   = e0-e2;
    adjF[base+2*cs] = e3-e1;
    adjF[base+3*cs] = e0-e1+e2-e3;
  }
}

// ---------------- build packed weight comps ----------------
// WA0p [c][48][32][4]: q=0: Wxz0/Whz0 ; q=1: Wxr0/Whr0 ; q=2: Wxh0 (k<16) else 0 ; q=3: 0
// WA1p [c][64][32][4]: same with KX=32, layer-1 weights
// WB0p/WB1p [k][o][c]: comps of Whr0/Whr1
__global__ __launch_bounds__(256) void k_wts(
    const float* __restrict__ Wxz0, const float* __restrict__ Wxr0, const float* __restrict__ Wxh0,
    const float* __restrict__ Whz0, const float* __restrict__ Whr0,
    const float* __restrict__ Wxz1, const float* __restrict__ Wxr1, const float* __restrict__ Wxh1,
    const float* __restrict__ Whz1, const float* __restrict__ Whr1,
    float* __restrict__ WA0p, float* __restrict__ WA1p,
    float* __restrict__ WB0p, float* __restrict__ WB1p) {
  int idx = blockIdx.x*256 + threadIdx.x;
  const float* src = nullptr;
  float* dst; int didx; int c;
  if (idx < SZ_WA0) {               // 24576
    c = idx / 6144;
    int rem = idx % 6144;
    int k = rem >> 7, og = (rem >> 2) & 31, q = rem & 3;
    if (q == 0) src = (k < FF) ? Wxz0 + ((size_t)k*HH + og)*4 : Whz0 + ((size_t)(k-FF)*HH + og)*4;
    else if (q == 1) src = (k < FF) ? Wxr0 + ((size_t)k*HH + og)*4 : Whr0 + ((size_t)(k-FF)*HH + og)*4;
    else if (q == 2 && k < FF) src = Wxh0 + ((size_t)k*HH + og)*4;
    dst = WA0p; didx = idx;
  } else if (idx < SZ_WA0 + SZ_WA1) {  // +32768
    int id = idx - SZ_WA0;
    c = id >> 13;
    int rem = id & 8191;
    int k = rem >> 7, og = (rem >> 2) & 31, q = rem & 3;
    if (q == 0) src = (k < HH) ? Wxz1 + ((size_t)k*HH + og)*4 : Whz1 + ((size_t)(k-HH)*HH + og)*4;
    else if (q == 1) src = (k < HH) ? Wxr1 + ((size_t)k*HH + og)*4 : Whr1 + ((size_t)(k-HH)*HH + og)*4;
    else if (q == 2 && k < HH) src = Wxh1 + ((size_t)k*HH + og)*4;
    dst = WA1p; didx = id;
  } else if (idx < SZ_WA0 + SZ_WA1 + SZ_WB) {
    int id = idx - (SZ_WA0 + SZ_WA1);
    int k = id >> 7, o = (id >> 2) & 31;
    c = id & 3;
    src = Whr0 + ((size_t)k*HH + o)*4;
    dst = WB0p; didx = id;
  } else if (idx < SZ_WA0 + SZ_WA1 + 2*SZ_WB) {
    int id = idx - (SZ_WA0 + SZ_WA1 + SZ_WB);
    int k = id >> 7, o = (id >> 2) & 31;
    c = id & 3;
    src = Whr1 + ((size_t)k*HH + o)*4;
    dst = WB1p; didx = id;
  } else return;
  float v0=0,v1=0,v2=0,v3=0;
  if (src) { v0=src[0]; v1=src[1]; v2=src[2]; v3=src[3]; }
  dst[didx] = comp_of4(v0,v1,v2,v3,c);
}

// ---------------- facewise aggregation: P[c][n][col] = (Af . X)[c] ----------------
// 32n x 32col tiles; thread = (ti=row, tj -> 4 cols)
struct AggParams {
  const float* X0; const float* X1; const float* X2;
  float* P0; float* P1; float* P2;
  int ncol0, ncol1, ncol2;
  int base1, base2, njobs, rawt;
};
__global__ __launch_bounds__(256,4) void k_agg(AggParams pr, const float* __restrict__ adjF,
                                               const float* __restrict__ inp) {
  __shared__ float As[4*32*37];   // [c][kk][i] stride 37 (odd -> conflict-free reads)
  __shared__ float Xs[4*32*36];   // [c][kk][col] stride 36 (16B-aligned f4 writes)
  int bid = blockIdx.x;
  const float* X; float* P; int ncol; int tile; bool raw = false;
  if (pr.njobs >= 3 && bid >= pr.base2) { X = pr.X2; P = pr.P2; ncol = pr.ncol2; tile = bid - pr.base2; }
  else if (pr.njobs >= 2 && bid >= pr.base1) { X = pr.X1; P = pr.P1; ncol = pr.ncol1; tile = bid - pr.base1; }
  else { X = pr.X0; P = pr.P0; ncol = pr.ncol0; tile = bid; raw = (pr.rawt >= 0); }
  int n0 = (tile % 5) * 32;
  int col0 = (tile / 5) * 32;
  int tid = threadIdx.x;
  int ti = tid & 31, tj = tid >> 5;
  int j0 = tj * 4;
  float a0[4]={}, aR[4]={}, aI[4]={}, a2v[4]={};
  for (int k0 = 0; k0 < NN; k0 += 32) {
    __syncthreads();
    #pragma unroll
    for (int u = 0; u < 16; ++u) {
      int e = tid + u * 256;
      int c = e >> 10, rem = e & 1023, i = rem >> 5, kk = rem & 31;
      int nn_ = n0 + i, mm = k0 + kk;
      float v = 0.f;
      if (nn_ < NN && mm < NN) v = adjF[((size_t)c * NN + nn_) * NN + mm];
      As[(c*32 + kk)*37 + i] = v;
    }
    if (raw) {
      // 256 groups: q = tid&7 (4 cols), kk = tid>>3
      int q = tid & 7, kk = tid >> 3;
      int mm = k0 + kk;
      int col = col0 + q*4;
      int b = col >> 4, f = col & 15;
      float4 r0 = make_float4(0,0,0,0), r1 = r0, r2 = r0, r3 = r0;
      if (mm < NN) {
        const float* s = inp + (((size_t)(b*TT + pr.rawt)*NN + mm)*FF + f)*4;
        r0 = *(const float4*)(s+0);
        r1 = *(const float4*)(s+4);
        r2 = *(const float4*)(s+8);
        r3 = *(const float4*)(s+12);
      }
      float4 w;
      w = make_float4(r0.x+r0.y+r0.z+r0.w, r1.x+r1.y+r1.z+r1.w, r2.x+r2.y+r2.z+r2.w, r3.x+r3.y+r3.z+r3.w);
      *(float4*)&Xs[(0*32+kk)*36 + q*4] = w;
      w = make_float4(r0.x-r0.z, r1.x-r1.z, r2.x-r2.z, r3.x-r3.z);
      *(float4*)&Xs[(1*32+kk)*36 + q*4] = w;
      w = make_float4(r0.w-r0.y, r1.w-r1.y, r2.w-r2.y, r3.w-r3.y);
      *(float4*)&Xs[(2*32+kk)*36 + q*4] = w;
      w = make_float4(r0.x-r0.y+r0.z-r0.w, r1.x-r1.y+r1.z-r1.w, r2.x-r2.y+r2.z-r2.w, r3.x-r3.y+r3.z-r3.w);
      *(float4*)&Xs[(3*32+kk)*36 + q*4] = w;
    } else {
      #pragma unroll
      for (int u = 0; u < 4; ++u) {
        int e = tid + u*256;            // 1024 float4s
        int c = e >> 8, rem = e & 255, kk = rem >> 3, q = rem & 7;
        int mm = k0 + kk;
        float4 v = make_float4(0,0,0,0);
        if (mm < NN) v = *(const float4*)(X + ((size_t)c*NN + mm)*ncol + col0 + q*4);
        *(float4*)&Xs[(c*32+kk)*36 + q*4] = v;
      }
    }
    __syncthreads();
    #pragma unroll 4
    for (int k = 0; k < 32; ++k) {
      float A0 = As[(0*32+k)*37 + ti];
      float A1 = As[(1*32+k)*37 + ti];
      float A2 = As[(2*32+k)*37 + ti];
      float A3 = As[(3*32+k)*37 + ti];
      float4 x0 = *(float4*)&Xs[(0*32+k)*36 + j0];
      float4 x1 = *(float4*)&Xs[(1*32+k)*36 + j0];
      float4 x2 = *(float4*)&Xs[(2*32+k)*36 + j0];
      float4 x3 = *(float4*)&Xs[(3*32+k)*36 + j0];
      float X0v[4]={x0.x,x0.y,x0.z,x0.w}, X1v[4]={x1.x,x1.y,x1.z,x1.w};
      float X2v[4]={x2.x,x2.y,x2.z,x2.w}, X3v[4]={x3.x,x3.y,x3.z,x3.w};
      #pragma unroll
      for (int j = 0; j < 4; ++j) {
        a0[j] += A0*X0v[j];
        aR[j] += A1*X1v[j] - A2*X2v[j];
        aI[j] += A1*X2v[j] + A2*X1v[j];
        a2v[j] += A3*X3v[j];
      }
    }
  }
  int nn_ = n0 + ti;
  if (nn_ < NN) {
    size_t cs = (size_t)NN*ncol;
    size_t rb = (size_t)nn_*ncol + col0 + j0;
    *(float4*)&P[rb]      = make_float4(a0[0],a0[1],a0[2],a0[3]);
    *(float4*)&P[rb+cs]   = make_float4(aR[0],aR[1],aR[2],aR[3]);
    *(float4*)&P[rb+2*cs] = make_float4(aI[0],aI[1],aI[2],aI[3]);
    *(float4*)&P[rb+3*cs] = make_float4(a2v[0],a2v[1],a2v[2],a2v[3]);
  }
}

// ---------------- phase A: transform + gates -> Z, T1, Mf ----------------
struct FAJob {
  const float* Px;   // [c][ROWS][Kx]
  const float* Ph;   // [c][ROWS][32]
  const float* W;    // packed [c][Ktot][32][4]
  const float* bias; // raw B ptr [3][32][4]
  const float* hprev;// [ROWS][32][4]
  float* Z; float* T1; float* Mf;
  int zh;
};
struct FAParams { FAJob j[2]; };

template<int KTOT, int KX>
__device__ __forceinline__ void fusedA_body(const FAJob& jb, float* Ps) {
  int row0 = blockIdx.x * 8;
  int tid = threadIdx.x;
  int r = tid >> 5, og = tid & 31;
  int row = row0 + r;
  // stage P comps packed [r][k][c] (written & read by the same half-wave)
  for (int kk = og; kk < KTOT; kk += 32) {
    #pragma unroll
    for (int c = 0; c < 4; ++c) {
      float v;
      if (kk < KX) v = jb.Px[((size_t)c*ROWS + row)*KX + kk];
      else         v = jb.zh ? 0.f : jb.Ph[((size_t)c*ROWS + row)*HH + (kk-KX)];
      Ps[(r*KTOT + kk)*4 + c] = v;
    }
  }
  __syncthreads();
  float acc0[3]={}, accR[3]={}, accI[3]={}, acc2[3]={};
  const float* W = jb.W;
  #pragma unroll 4
  for (int k = 0; k < KTOT; ++k) {
    float4 p  = *(const float4*)&Ps[(r*KTOT + k)*4];
    float4 w0 = *(const float4*)&W[((size_t)(0*KTOT + k)*32 + og)*4];
    float4 w1 = *(const float4*)&W[((size_t)(1*KTOT + k)*32 + og)*4];
    float4 w2 = *(const float4*)&W[((size_t)(2*KTOT + k)*32 + og)*4];
    float4 w3 = *(const float4*)&W[((size_t)(3*KTOT + k)*32 + og)*4];
    float W0v[3]={w0.x,w0.y,w0.z}, W1v[3]={w1.x,w1.y,w1.z};
    float W2v[3]={w2.x,w2.y,w2.z}, W3v[3]={w3.x,w3.y,w3.z};
    #pragma unroll
    for (int q = 0; q < 3; ++q) {
      acc0[q] += p.x*W0v[q];
      accR[q] += p.y*W1v[q] - p.z*W2v[q];
      accI[q] += p.y*W2v[q] + p.z*W1v[q];
      acc2[q] += p.w*W3v[q];
    }
  }
  // epilogue: q=0 -> Z (o=og), q=1 -> M (oc=og), q=2 -> T1 (oc=og)
  float ys[3][4];
  #pragma unroll
  for (int q = 0; q < 3; ++q) {
    float Y0 = acc0[q], Yr = accR[q], Yi = accI[q], Y2 = acc2[q];
    ys[q][0] = 0.25f*(Y0 + 2.f*Yr + Y2);
    ys[q][1] = 0.25f*(Y0 - 2.f*Yi - Y2);
    ys[q][2] = 0.25f*(Y0 - 2.f*Yr + Y2);
    ys[q][3] = 0.25f*(Y0 + 2.f*Yi - Y2);
  }
  {
    const float* bz = jb.bias + (0*HH + og)*4;
    float4 z = make_float4(sigmoidf_(ys[0][0]+bz[0]), sigmoidf_(ys[0][1]+bz[1]),
                           sigmoidf_(ys[0][2]+bz[2]), sigmoidf_(ys[0][3]+bz[3]));
    *(float4*)&jb.Z[((size_t)row*HH + og)*4] = z;
  }
  {
    const float* br = jb.bias + (1*HH + og)*4;
    float4 hp = make_float4(0,0,0,0);
    if (!jb.zh) hp = *(const float4*)&jb.hprev[((size_t)row*HH + og)*4];
    float m0 = sigmoidf_(ys[1][0]+br[0]) * hp.x;
    float m1 = sigmoidf_(ys[1][1]+br[1]) * hp.y;
    float m2 = sigmoidf_(ys[1][2]+br[2]) * hp.z;
    float m3 = sigmoidf_(ys[1][3]+br[3]) * hp.w;
    size_t mb = (size_t)row*HH + og;
    size_t cs = (size_t)ROWS*HH;
    jb.Mf[mb]      = m0+m1+m2+m3;
    jb.Mf[mb+cs]   = m0-m2;
    jb.Mf[mb+2*cs] = m3-m1;
    jb.Mf[mb+3*cs] = m0-m1+m2-m3;
  }
  {
    const float* bh = jb.bias + (2*HH + og)*4;
    float4 tv = make_float4(ys[2][0]+bh[0], ys[2][1]+bh[1], ys[2][2]+bh[2], ys[2][3]+bh[3]);
    *(float4*)&jb.T1[((size_t)row*HH + og)*4] = tv;
  }
}

__global__ __launch_bounds__(256,4) void k_fusedA_both(FAParams pr) {
  __shared__ float Ps[8*64*4];
  if (blockIdx.y == 0) fusedA_body<48,16>(pr.j[0], Ps);
  else                 fusedA_body<64,32>(pr.j[1], Ps);
}
__global__ __launch_bounds__(256,4) void k_fusedA_L0(FAParams pr) {
  __shared__ float Ps[8*48*4];
  fusedA_body<48,16>(pr.j[0], Ps);
}
__global__ __launch_bounds__(256,4) void k_fusedA_L1(FAParams pr) {
  __shared__ float Ps[8*64*4];
  fusedA_body<64,32>(pr.j[1], Ps);
}

// ---------------- phase B: Ht=tanh(T1+ifft(Pm.W)); Hnew=Z*Hprev+(1-Z)*Ht ----------------
struct FBJob {
  const float* Pm; const float* W; const float* T1; const float* Z;
  float* h; float* hf; float* outp;
  int t, zh, wout;
};
struct FBParams { FBJob j[2]; };
__global__ __launch_bounds__(256,4) void k_fusedB(FBParams pr) {
  __shared__ float Ps[8*32*4];
  FBJob jb = pr.j[blockIdx.y];
  int row0 = blockIdx.x * 8;
  int tid = threadIdx.x;
  int r = tid >> 5, o = tid & 31;
  int row = row0 + r;
  float acc0=0, accR=0, accI=0, acc2=0;
  if (!jb.zh) {
    #pragma unroll
    for (int c = 0; c < 4; ++c)
      Ps[(r*32 + o)*4 + c] = jb.Pm[((size_t)c*ROWS + row)*HH + o];
    __syncthreads();
    #pragma unroll 8
    for (int k = 0; k < 32; ++k) {
      float4 p = *(const float4*)&Ps[(r*32 + k)*4];
      float4 w = *(const float4*)&jb.W[((size_t)(k*32 + o))*4];   // [k][o][c]
      acc0 += p.x*w.x;
      accR += p.y*w.y - p.z*w.z;
      accI += p.y*w.z + p.z*w.y;
      acc2 += p.w*w.w;
    }
  }
  float y0 = 0.25f*(acc0 + 2.f*accR + acc2);
  float y1 = 0.25f*(acc0 - 2.f*accI - acc2);
  float y2 = 0.25f*(acc0 - 2.f*accR + acc2);
  float y3 = 0.25f*(acc0 + 2.f*accI - acc2);
  float4 t1 = *(const float4*)&jb.T1[((size_t)row*HH + o)*4];
  float h0v = tanhf(t1.x + y0);
  float h1v = tanhf(t1.y + y1);
  float h2v = tanhf(t1.z + y2);
  float h3v = tanhf(t1.w + y3);
  float4 z = *(const float4*)&jb.Z[((size_t)row*HH + o)*4];
  float4 hp = make_float4(0,0,0,0);
  if (!jb.zh) hp = *(const float4*)&jb.h[((size_t)row*HH + o)*4];
  float n0v = z.x*hp.x + (1.f-z.x)*h0v;
  float n1v = z.y*hp.y + (1.f-z.y)*h1v;
  float n2v = z.z*hp.z + (1.f-z.z)*h2v;
  float n3v = z.w*hp.w + (1.f-z.w)*h3v;
  *(float4*)&jb.h[((size_t)row*HH + o)*4] = make_float4(n0v,n1v,n2v,n3v);
  size_t hb = (size_t)row*HH + o, cs = (size_t)ROWS*HH;
  jb.hf[hb]      = n0v+n1v+n2v+n3v;
  jb.hf[hb+cs]   = n0v-n2v;
  jb.hf[hb+2*cs] = n3v-n1v;
  jb.hf[hb+3*cs] = n0v-n1v+n2v-n3v;
  if (jb.wout) {
    int n = row >> 5, b = row & 31;
    float* dst = jb.outp + (((size_t)b*TT + jb.t)*NN + n)*(HH*4) + o*4;
    *(float4*)dst = make_float4(n0v,n1v,n2v,n3v);
  }
}

// ---------------- h_last: [2][B][N][H][R] from h buffers [n*32+b][H][4] ----------------
__global__ __launch_bounds__(256) void k_hlast(const float* __restrict__ h0, const float* __restrict__ h1,
                                               float* __restrict__ dst) {
  int idx = blockIdx.x*256 + threadIdx.x;
  if (idx >= 2*BB*NN*HH*4) return;
  int hr = idx & 127;
  int n = (idx >> 7) % NN;
  int rest = idx / (128*NN);
  int b = rest & 31;
  int l = rest >> 5;
  const float* src = (l ? h1 : h0);
  dst[idx] = src[((size_t)(n*BB + b))*128 + hr];
}

extern "C" void kernel_launch(void* const* d_in, const int* in_sizes, int n_in,
                              void* d_out, int out_size, void* d_ws, size_t ws_size,
                              hipStream_t stream) {
  const float* inp  = (const float*)d_in[0];
  const float* U    = (const float*)d_in[1];
  const float* Wxz0 = (const float*)d_in[2];
  const float* Wxr0 = (const float*)d_in[3];
  const float* Wxh0 = (const float*)d_in[4];
  const float* Whz0 = (const float*)d_in[5];
  const float* Whr0 = (const float*)d_in[6];
  const float* B0   = (const float*)d_in[7];
  const float* Wxz1 = (const float*)d_in[8];
  const float* Wxr1 = (const float*)d_in[9];
  const float* Wxh1 = (const float*)d_in[10];
  const float* Whz1 = (const float*)d_in[11];
  const float* Whr1 = (const float*)d_in[12];
  const float* B1   = (const float*)d_in[13];
  float* out = (float*)d_out;

  float* ws = (float*)d_ws;
  float* ADJF = ws;  ws += SZ_ADJF;
  float* WA0  = ws;  ws += SZ_WA0;
  float* WA1  = ws;  ws += SZ_WA1;
  float* WB0  = ws;  ws += SZ_WB;
  float* WB1  = ws;  ws += SZ_WB;
  float* H0   = ws;  ws += SZ_STATE;
  float* H1   = ws;  ws += SZ_STATE;
  float* H0F  = ws;  ws += SZ_STATE;
  float* H1F  = ws;  ws += SZ_STATE;
  float* PIN  = ws;  ws += SZ_PIN;
  float* PH0  = ws;  ws += SZ_STATE;
  float* PH1  = ws;  ws += SZ_STATE;
  float* PM0  = ws;  ws += SZ_STATE;
  float* PM1  = ws;  ws += SZ_STATE;
  float* M0F  = ws;  ws += SZ_STATE;
  float* M1F  = ws;  ws += SZ_STATE;
  float* Z0   = ws;  ws += SZ_STATE;
  float* Z1   = ws;  ws += SZ_STATE;
  float* T10  = ws;  ws += SZ_STATE;
  float* T11  = ws;  ws += SZ_STATE;

  k_adj<<<NN, 256, 0, stream>>>(U, ADJF);
  k_wts<<<(SZ_WA0+SZ_WA1+2*SZ_WB+255)/256, 256, 0, stream>>>(
      Wxz0,Wxr0,Wxh0,Whz0,Whr0,Wxz1,Wxr1,Wxh1,Whz1,Whr1,WA0,WA1,WB0,WB1);

  // ---- t = 0 (zero hidden) ----
  {
    AggParams p; p.X0=nullptr; p.P0=PIN; p.ncol0=NCIN;
    p.X1=nullptr; p.P1=nullptr; p.ncol1=0; p.X2=nullptr; p.P2=nullptr; p.ncol2=0;
    p.base1=0; p.base2=0; p.njobs=1; p.rawt=0;
    k_agg<<<80, 256, 0, stream>>>(p, ADJF, inp);   // 5 n-tiles x 16 col-tiles
  }
  {
    FAParams p;
    p.j[0] = FAJob{PIN, nullptr, WA0, B0, nullptr, Z0, T10, M0F, 1};
    p.j[1] = p.j[0];
    k_fusedA_L0<<<dim3(600,1), 256, 0, stream>>>(p);
  }
  {
    FBParams p;
    p.j[0] = FBJob{nullptr, WB0, T10, Z0, H0, H0F, nullptr, 0, 1, 0};
    p.j[1] = p.j[0];
    k_fusedB<<<dim3(600,1), 256, 0, stream>>>(p);
  }
  {
    AggParams p; p.X0=H0F; p.P0=PH0; p.ncol0=NCH;
    p.X1=nullptr; p.P1=nullptr; p.ncol1=0; p.X2=nullptr; p.P2=nullptr; p.ncol2=0;
    p.base1=0; p.base2=0; p.njobs=1; p.rawt=-1;
    k_agg<<<160, 256, 0, stream>>>(p, ADJF, inp);  // 5 x 32
  }
  {
    FAParams p;
    p.j[0] = FAJob{PH0, nullptr, WA1, B1, nullptr, Z1, T11, M1F, 1};
    p.j[1] = p.j[0];
    k_fusedA_L1<<<dim3(600,1), 256, 0, stream>>>(p);
  }
  {
    FBParams p;
    p.j[0] = FBJob{nullptr, WB1, T11, Z1, H1, H1F, out, 0, 1, 1};
    p.j[1] = p.j[0];
    k_fusedB<<<dim3(600,1), 256, 0, stream>>>(p);
  }

  // ---- t = 1..7 ----
  for (int t = 1; t < TT; ++t) {
    {
      AggParams p;
      p.X0=nullptr; p.P0=PIN; p.ncol0=NCIN;   // raw inputs at t  (80 blocks)
      p.X1=H0F; p.P1=PH0; p.ncol1=NCH;        // agg of h0_prev   (160)
      p.X2=H1F; p.P2=PH1; p.ncol2=NCH;        // agg of h1_prev   (160)
      p.base1=80; p.base2=240; p.njobs=3; p.rawt=t;
      k_agg<<<400, 256, 0, stream>>>(p, ADJF, inp);
    }
    {
      FAParams p;
      p.j[0] = FAJob{PIN, PH0, WA0, B0, H0, Z0, T10, M0F, 0};
      p.j[1] = FAJob{PH0, PH1, WA1, B1, H1, Z1, T11, M1F, 0};
      k_fusedA_both<<<dim3(600,2), 256, 0, stream>>>(p);
    }
    {
      AggParams p;
      p.X0=M0F; p.P0=PM0; p.ncol0=NCH;
      p.X1=M1F; p.P1=PM1; p.ncol1=NCH;
      p.X2=nullptr; p.P2=nullptr; p.ncol2=0;
      p.base1=160; p.base2=0; p.njobs=2; p.rawt=-1;
      k_agg<<<320, 256, 0, stream>>>(p, ADJF, inp);
    }
    {
      FBParams p;
      p.j[0] = FBJob{PM0, WB0, T10, Z0, H0, H0F, nullptr, t, 0, 0};
      p.j[1] = FBJob{PM1, WB1, T11, Z1, H1, H1F, out, t, 0, 1};
      k_fusedB<<<dim3(600,2), 256, 0, stream>>>(p);
    }
  }
  k_hlast<<<(2*BB*NN*HH*4 + 255)/256, 256, 0, stream>>>(H0, H1, out + (size_t)BB*TT*NN*HH*4);
}

// Round 3
// 884.485 us; speedup vs baseline: 1.9464x; 1.3615x over previous
//
#include <hip/hip_runtime.h>
#include <math.h>

// Problem constants
#define NN 150   // nodes
#define BB 32    // batch
#define TT 8     // time
#define FF 16    // input features
#define HH 32    // hidden
#define ROWS (NN*BB)     // 4800 (row index = n*32 + b)
#define NCIN (BB*FF)     // 512
#define NCH  (BB*HH)     // 1024
#define ADJ_LD 160       // padded adjacency row stride (zero-filled 150..159)

// workspace sizes (floats)
#define SZ_ADJF (4*NN*ADJ_LD)
#define SZ_WA0  (4*48*32*4)   // packed [c][48][32][4]
#define SZ_WA1  (4*64*32*4)   // packed [c][64][32][4]
#define SZ_WB   (32*32*4)     // packed [k][o][c]
#define SZ_STATE (ROWS*HH*4)
#define SZ_PIN  (4*NN*NCIN)

__device__ __forceinline__ float sigmoidf_(float x){ return 1.f/(1.f+expf(-x)); }

__device__ __forceinline__ float comp_of4(float x0, float x1, float x2, float x3, int c) {
  return c==0 ? (x0+x1+x2+x3) : c==1 ? (x0-x2) : c==2 ? (x3-x1) : (x0-x1+x2-x3);
}

// Fourier comps of a real length-4 tube: c0, c1re, c1im, c2 (face3 = conj(face1))
// ifft: y0=(c0+2c1re+c2)/4; y1=(c0-2c1im-c2)/4; y2=(c0-2c1re+c2)/4; y3=(c0+2c1im-c2)/4

// ---------------- adjacency: softmax(relu(ifft(Uf Uf^T))) then comps (padded LD=160) ----------------
__global__ __launch_bounds__(256) void k_adj(const float* __restrict__ U, float* __restrict__ adjF) {
  __shared__ float Ufl[NN*16*4];
  __shared__ float Arow[NN*4];
  __shared__ float red[256];
  __shared__ float mxs[4], isms[4];
  int n = blockIdx.x, tid = threadIdx.x;
  for (int idx = tid; idx < NN*16; idx += 256) {
    const float* s = U + (size_t)idx*4;
    float x0=s[0], x1=s[1], x2=s[2], x3=s[3];
    Ufl[idx*4+0] = x0+x1+x2+x3;
    Ufl[idx*4+1] = x0-x2;
    Ufl[idx*4+2] = x3-x1;
    Ufl[idx*4+3] = x0-x1+x2-x3;
  }
  __syncthreads();
  if (tid < NN) {
    int m = tid;
    float a0=0, ar=0, ai=0, a2=0;
    #pragma unroll
    for (int e = 0; e < 16; ++e) {
      const float* un = &Ufl[(n*16+e)*4];
      const float* um = &Ufl[(m*16+e)*4];
      a0 += un[0]*um[0];
      ar += un[1]*um[1] - un[2]*um[2];
      ai += un[1]*um[2] + un[2]*um[1];
      a2 += un[3]*um[3];
    }
    float r0 = 0.25f*(a0 + 2.f*ar + a2);
    float r1 = 0.25f*(a0 - 2.f*ai - a2);
    float r2 = 0.25f*(a0 - 2.f*ar + a2);
    float r3 = 0.25f*(a0 + 2.f*ai - a2);
    Arow[m*4+0] = fmaxf(r0, 0.f);
    Arow[m*4+1] = fmaxf(r1, 0.f);
    Arow[m*4+2] = fmaxf(r2, 0.f);
    Arow[m*4+3] = fmaxf(r3, 0.f);
  }
  __syncthreads();
  for (int r = 0; r < 4; ++r) {
    float v = (tid < NN) ? Arow[tid*4+r] : -1e30f;
    red[tid] = v; __syncthreads();
    for (int s = 128; s > 0; s >>= 1) { if (tid < s) red[tid] = fmaxf(red[tid], red[tid+s]); __syncthreads(); }
    if (tid == 0) mxs[r] = red[0];
    __syncthreads();
    float e = (tid < NN) ? expf(Arow[tid*4+r] - mxs[r]) : 0.f;
    red[tid] = e; __syncthreads();
    for (int s = 128; s > 0; s >>= 1) { if (tid < s) red[tid] += red[tid+s]; __syncthreads(); }
    if (tid == 0) isms[r] = 1.f / red[0];
    __syncthreads();
    if (tid < NN) Arow[tid*4+r] = e * isms[r];
    __syncthreads();
  }
  if (tid < NN) {
    int m = tid;
    float e0=Arow[m*4+0], e1=Arow[m*4+1], e2=Arow[m*4+2], e3=Arow[m*4+3];
    size_t base = (size_t)n*ADJ_LD + m;
    size_t cs = (size_t)NN*ADJ_LD;
    adjF[base]      = e0+e1+e2+e3;
    adjF[base+cs]   = e0-e2;
    adjF[base+2*cs] = e3-e1;
    adjF[base+3*cs] = e0-e1+e2-e3;
  } else if (tid < ADJ_LD) {
    size_t base = (size_t)n*ADJ_LD + tid;
    size_t cs = (size_t)NN*ADJ_LD;
    adjF[base] = 0.f; adjF[base+cs] = 0.f; adjF[base+2*cs] = 0.f; adjF[base+3*cs] = 0.f;
  }
}

// ---------------- build packed weight comps ----------------
__global__ __launch_bounds__(256) void k_wts(
    const float* __restrict__ Wxz0, const float* __restrict__ Wxr0, const float* __restrict__ Wxh0,
    const float* __restrict__ Whz0, const float* __restrict__ Whr0,
    const float* __restrict__ Wxz1, const float* __restrict__ Wxr1, const float* __restrict__ Wxh1,
    const float* __restrict__ Whz1, const float* __restrict__ Whr1,
    float* __restrict__ WA0p, float* __restrict__ WA1p,
    float* __restrict__ WB0p, float* __restrict__ WB1p) {
  int idx = blockIdx.x*256 + threadIdx.x;
  const float* src = nullptr;
  float* dst; int didx; int c;
  if (idx < SZ_WA0) {               // 24576
    c = idx / 6144;
    int rem = idx % 6144;
    int k = rem >> 7, og = (rem >> 2) & 31, q = rem & 3;
    if (q == 0) src = (k < FF) ? Wxz0 + ((size_t)k*HH + og)*4 : Whz0 + ((size_t)(k-FF)*HH + og)*4;
    else if (q == 1) src = (k < FF) ? Wxr0 + ((size_t)k*HH + og)*4 : Whr0 + ((size_t)(k-FF)*HH + og)*4;
    else if (q == 2 && k < FF) src = Wxh0 + ((size_t)k*HH + og)*4;
    dst = WA0p; didx = idx;
  } else if (idx < SZ_WA0 + SZ_WA1) {  // +32768
    int id = idx - SZ_WA0;
    c = id >> 13;
    int rem = id & 8191;
    int k = rem >> 7, og = (rem >> 2) & 31, q = rem & 3;
    if (q == 0) src = (k < HH) ? Wxz1 + ((size_t)k*HH + og)*4 : Whz1 + ((size_t)(k-HH)*HH + og)*4;
    else if (q == 1) src = (k < HH) ? Wxr1 + ((size_t)k*HH + og)*4 : Whr1 + ((size_t)(k-HH)*HH + og)*4;
    else if (q == 2 && k < HH) src = Wxh1 + ((size_t)k*HH + og)*4;
    dst = WA1p; didx = id;
  } else if (idx < SZ_WA0 + SZ_WA1 + SZ_WB) {
    int id = idx - (SZ_WA0 + SZ_WA1);
    int k = id >> 7, o = (id >> 2) & 31;
    c = id & 3;
    src = Whr0 + ((size_t)k*HH + o)*4;
    dst = WB0p; didx = id;
  } else if (idx < SZ_WA0 + SZ_WA1 + 2*SZ_WB) {
    int id = idx - (SZ_WA0 + SZ_WA1 + SZ_WB);
    int k = id >> 7, o = (id >> 2) & 31;
    c = id & 3;
    src = Whr1 + ((size_t)k*HH + o)*4;
    dst = WB1p; didx = id;
  } else return;
  float v0=0,v1=0,v2=0,v3=0;
  if (src) { v0=src[0]; v1=src[1]; v2=src[2]; v3=src[3]; }
  dst[didx] = comp_of4(v0,v1,v2,v3,c);
}

// ---------------- facewise aggregation with split-K and register prefetch ----------------
// P partial layout: part p at P + p*4*NN*ncol ; consumers sum both parts.
struct AggParams {
  const float* X0; const float* X1; const float* X2;
  float* P0; float* P1; float* P2;
  int ncol0, ncol1, ncol2;
  int base1, base2, njobs, rawt, nb;   // nb = blocks per K-part; grid = 2*nb
};
__global__ __launch_bounds__(256,4) void k_agg(AggParams pr, const float* __restrict__ adjF,
                                               const float* __restrict__ inp) {
  __shared__ float As[4*32*37];   // [c][kk][i] stride 37
  __shared__ float Xs[4*32*36];   // [c][kk][col] stride 36
  int bid = blockIdx.x;
  int part = (bid >= pr.nb) ? 1 : 0;
  if (part) bid -= pr.nb;
  const float* X; float* P; int ncol; int tile; bool raw = false;
  if (pr.njobs >= 3 && bid >= pr.base2) { X = pr.X2; P = pr.P2; ncol = pr.ncol2; tile = bid - pr.base2; }
  else if (pr.njobs >= 2 && bid >= pr.base1) { X = pr.X1; P = pr.P1; ncol = pr.ncol1; tile = bid - pr.base1; }
  else { X = pr.X0; P = pr.P0; ncol = pr.ncol0; tile = bid; raw = (pr.rawt >= 0); }
  P += (size_t)part * 4 * NN * ncol;
  int kbeg = part ? 96 : 0;
  int kend = part ? NN : 96;
  int n0 = (tile % 5) * 32;
  int col0 = (tile / 5) * 32;
  int tid = threadIdx.x;
  int ti = tid & 31, tj = tid >> 5;
  int j0 = tj * 4;
  float a0[4]={}, aR[4]={}, aI[4]={}, a2v[4]={};

  // prefetch registers
  float4 pa[4];   // A tile: thread u<4 -> (c,i,kq)
  float4 px[4];   // X tile (generic) or raw 16 floats

  // ---- load helpers (inlined manually) ----
  // A: 1024 float4s: e = tid + u*256 ; c=e>>8, rem=e&255, i=rem>>3, kq=rem&7
  #define LOAD_A(K0)                                                         \
    _Pragma("unroll")                                                        \
    for (int u = 0; u < 4; ++u) {                                            \
      int e = tid + u*256;                                                   \
      int c = e >> 8, rem = e & 255, i = rem >> 3, kq = rem & 7;             \
      int nn_ = n0 + i;                                                      \
      pa[u] = make_float4(0,0,0,0);                                          \
      if (nn_ < NN) pa[u] = *(const float4*)(adjF + ((size_t)c*NN + nn_)*ADJ_LD + (K0) + kq*4); \
    }
  #define STORE_A()                                                          \
    _Pragma("unroll")                                                        \
    for (int u = 0; u < 4; ++u) {                                            \
      int e = tid + u*256;                                                   \
      int c = e >> 8, rem = e & 255, i = rem >> 3, kq = rem & 7;             \
      As[(c*32 + kq*4+0)*37 + i] = pa[u].x;                                  \
      As[(c*32 + kq*4+1)*37 + i] = pa[u].y;                                  \
      As[(c*32 + kq*4+2)*37 + i] = pa[u].z;                                  \
      As[(c*32 + kq*4+3)*37 + i] = pa[u].w;                                  \
    }
  #define LOAD_X(K0)                                                         \
    if (raw) {                                                               \
      int q = tid & 7, kk = tid >> 3;                                        \
      int mm = (K0) + kk;                                                    \
      int col = col0 + q*4;                                                  \
      int b = col >> 4, f = col & 15;                                        \
      px[0]=px[1]=px[2]=px[3]=make_float4(0,0,0,0);                          \
      if (mm < NN) {                                                         \
        const float* s = inp + (((size_t)(b*TT + pr.rawt)*NN + mm)*FF + f)*4;\
        px[0] = *(const float4*)(s+0);                                       \
        px[1] = *(const float4*)(s+4);                                       \
        px[2] = *(const float4*)(s+8);                                       \
        px[3] = *(const float4*)(s+12);                                      \
      }                                                                      \
    } else {                                                                 \
      _Pragma("unroll")                                                      \
      for (int u = 0; u < 4; ++u) {                                          \
        int e = tid + u*256;                                                 \
        int c = e >> 8, rem = e & 255, kk = rem >> 3, q = rem & 7;           \
        int mm = (K0) + kk;                                                  \
        px[u] = make_float4(0,0,0,0);                                        \
        if (mm < NN) px[u] = *(const float4*)(X + ((size_t)c*NN + mm)*ncol + col0 + q*4); \
      }                                                                      \
    }
  #define STORE_X()                                                          \
    if (raw) {                                                               \
      int q = tid & 7, kk = tid >> 3;                                        \
      float4 r0 = px[0], r1 = px[1], r2 = px[2], r3 = px[3];                 \
      float4 w;                                                              \
      w = make_float4(r0.x+r0.y+r0.z+r0.w, r1.x+r1.y+r1.z+r1.w, r2.x+r2.y+r2.z+r2.w, r3.x+r3.y+r3.z+r3.w); \
      *(float4*)&Xs[(0*32+kk)*36 + q*4] = w;                                 \
      w = make_float4(r0.x-r0.z, r1.x-r1.z, r2.x-r2.z, r3.x-r3.z);           \
      *(float4*)&Xs[(1*32+kk)*36 + q*4] = w;                                 \
      w = make_float4(r0.w-r0.y, r1.w-r1.y, r2.w-r2.y, r3.w-r3.y);           \
      *(float4*)&Xs[(2*32+kk)*36 + q*4] = w;                                 \
      w = make_float4(r0.x-r0.y+r0.z-r0.w, r1.x-r1.y+r1.z-r1.w, r2.x-r2.y+r2.z-r2.w, r3.x-r3.y+r3.z-r3.w); \
      *(float4*)&Xs[(3*32+kk)*36 + q*4] = w;                                 \
    } else {                                                                 \
      _Pragma("unroll")                                                      \
      for (int u = 0; u < 4; ++u) {                                          \
        int e = tid + u*256;                                                 \
        int c = e >> 8, rem = e & 255, kk = rem >> 3, q = rem & 7;           \
        *(float4*)&Xs[(c*32+kk)*36 + q*4] = px[u];                           \
      }                                                                      \
    }

  LOAD_A(kbeg)
  LOAD_X(kbeg)
  for (int k0 = kbeg; k0 < kend; k0 += 32) {
    STORE_A()
    STORE_X()
    __syncthreads();
    int k0n = k0 + 32;
    if (k0n < kend) {
      LOAD_A(k0n)
      LOAD_X(k0n)
    }
    #pragma unroll 4
    for (int k = 0; k < 32; ++k) {
      float A0 = As[(0*32+k)*37 + ti];
      float A1 = As[(1*32+k)*37 + ti];
      float A2 = As[(2*32+k)*37 + ti];
      float A3 = As[(3*32+k)*37 + ti];
      float4 x0 = *(float4*)&Xs[(0*32+k)*36 + j0];
      float4 x1 = *(float4*)&Xs[(1*32+k)*36 + j0];
      float4 x2 = *(float4*)&Xs[(2*32+k)*36 + j0];
      float4 x3 = *(float4*)&Xs[(3*32+k)*36 + j0];
      float X0v[4]={x0.x,x0.y,x0.z,x0.w}, X1v[4]={x1.x,x1.y,x1.z,x1.w};
      float X2v[4]={x2.x,x2.y,x2.z,x2.w}, X3v[4]={x3.x,x3.y,x3.z,x3.w};
      #pragma unroll
      for (int j = 0; j < 4; ++j) {
        a0[j] += A0*X0v[j];
        aR[j] += A1*X1v[j] - A2*X2v[j];
        aI[j] += A1*X2v[j] + A2*X1v[j];
        a2v[j] += A3*X3v[j];
      }
    }
    __syncthreads();
  }
  int nn_ = n0 + ti;
  if (nn_ < NN) {
    size_t cs = (size_t)NN*ncol;
    size_t rb = (size_t)nn_*ncol + col0 + j0;
    *(float4*)&P[rb]      = make_float4(a0[0],a0[1],a0[2],a0[3]);
    *(float4*)&P[rb+cs]   = make_float4(aR[0],aR[1],aR[2],aR[3]);
    *(float4*)&P[rb+2*cs] = make_float4(aI[0],aI[1],aI[2],aI[3]);
    *(float4*)&P[rb+3*cs] = make_float4(a2v[0],a2v[1],a2v[2],a2v[3]);
  }
}

// ---------------- phase A: transform + gates -> Z, T1, Mf ----------------
struct FAJob {
  const float* Px;   // partial pair: [2][c][ROWS][Kx]
  const float* Ph;   // partial pair: [2][c][ROWS][32]
  const float* W;    // packed [c][Ktot][32][4]
  const float* bias;
  const float* hprev;
  float* Z; float* T1; float* Mf;
  int zh;
};
struct FAParams { FAJob j[2]; };

template<int KTOT, int KX>
__device__ __forceinline__ void fusedA_body(const FAJob& jb, float* Ps) {
  int row0 = blockIdx.x * 8;
  int tid = threadIdx.x;
  int r = tid >> 5, og = tid & 31;
  int row = row0 + r;
  const size_t psx = (size_t)4*ROWS*KX;
  const size_t psh = (size_t)4*ROWS*HH;
  for (int kk = og; kk < KTOT; kk += 32) {
    #pragma unroll
    for (int c = 0; c < 4; ++c) {
      float v;
      if (kk < KX) {
        size_t ix = ((size_t)c*ROWS + row)*KX + kk;
        v = jb.Px[ix] + jb.Px[ix + psx];
      } else {
        if (jb.zh) v = 0.f;
        else {
          size_t ih = ((size_t)c*ROWS + row)*HH + (kk-KX);
          v = jb.Ph[ih] + jb.Ph[ih + psh];
        }
      }
      Ps[(r*KTOT + kk)*4 + c] = v;
    }
  }
  __syncthreads();
  float acc0[3]={}, accR[3]={}, accI[3]={}, acc2[3]={};
  const float* W = jb.W;
  #pragma unroll 4
  for (int k = 0; k < KTOT; ++k) {
    float4 p  = *(const float4*)&Ps[(r*KTOT + k)*4];
    float4 w0 = *(const float4*)&W[((size_t)(0*KTOT + k)*32 + og)*4];
    float4 w1 = *(const float4*)&W[((size_t)(1*KTOT + k)*32 + og)*4];
    float4 w2 = *(const float4*)&W[((size_t)(2*KTOT + k)*32 + og)*4];
    float4 w3 = *(const float4*)&W[((size_t)(3*KTOT + k)*32 + og)*4];
    float W0v[3]={w0.x,w0.y,w0.z}, W1v[3]={w1.x,w1.y,w1.z};
    float W2v[3]={w2.x,w2.y,w2.z}, W3v[3]={w3.x,w3.y,w3.z};
    #pragma unroll
    for (int q = 0; q < 3; ++q) {
      acc0[q] += p.x*W0v[q];
      accR[q] += p.y*W1v[q] - p.z*W2v[q];
      accI[q] += p.y*W2v[q] + p.z*W1v[q];
      acc2[q] += p.w*W3v[q];
    }
  }
  float ys[3][4];
  #pragma unroll
  for (int q = 0; q < 3; ++q) {
    float Y0 = acc0[q], Yr = accR[q], Yi = accI[q], Y2 = acc2[q];
    ys[q][0] = 0.25f*(Y0 + 2.f*Yr + Y2);
    ys[q][1] = 0.25f*(Y0 - 2.f*Yi - Y2);
    ys[q][2] = 0.25f*(Y0 - 2.f*Yr + Y2);
    ys[q][3] = 0.25f*(Y0 + 2.f*Yi - Y2);
  }
  {
    const float* bz = jb.bias + (0*HH + og)*4;
    float4 z = make_float4(sigmoidf_(ys[0][0]+bz[0]), sigmoidf_(ys[0][1]+bz[1]),
                           sigmoidf_(ys[0][2]+bz[2]), sigmoidf_(ys[0][3]+bz[3]));
    *(float4*)&jb.Z[((size_t)row*HH + og)*4] = z;
  }
  {
    const float* br = jb.bias + (1*HH + og)*4;
    float4 hp = make_float4(0,0,0,0);
    if (!jb.zh) hp = *(const float4*)&jb.hprev[((size_t)row*HH + og)*4];
    float m0 = sigmoidf_(ys[1][0]+br[0]) * hp.x;
    float m1 = sigmoidf_(ys[1][1]+br[1]) * hp.y;
    float m2 = sigmoidf_(ys[1][2]+br[2]) * hp.z;
    float m3 = sigmoidf_(ys[1][3]+br[3]) * hp.w;
    size_t mb = (size_t)row*HH + og;
    size_t cs = (size_t)ROWS*HH;
    jb.Mf[mb]      = m0+m1+m2+m3;
    jb.Mf[mb+cs]   = m0-m2;
    jb.Mf[mb+2*cs] = m3-m1;
    jb.Mf[mb+3*cs] = m0-m1+m2-m3;
  }
  {
    const float* bh = jb.bias + (2*HH + og)*4;
    float4 tv = make_float4(ys[2][0]+bh[0], ys[2][1]+bh[1], ys[2][2]+bh[2], ys[2][3]+bh[3]);
    *(float4*)&jb.T1[((size_t)row*HH + og)*4] = tv;
  }
}

__global__ __launch_bounds__(256,4) void k_fusedA_both(FAParams pr) {
  __shared__ float Ps[8*64*4];
  if (blockIdx.y == 0) fusedA_body<48,16>(pr.j[0], Ps);
  else                 fusedA_body<64,32>(pr.j[1], Ps);
}
__global__ __launch_bounds__(256,4) void k_fusedA_L0(FAParams pr) {
  __shared__ float Ps[8*48*4];
  fusedA_body<48,16>(pr.j[0], Ps);
}
__global__ __launch_bounds__(256,4) void k_fusedA_L1(FAParams pr) {
  __shared__ float Ps[8*64*4];
  fusedA_body<64,32>(pr.j[1], Ps);
}

// ---------------- phase B ----------------
struct FBJob {
  const float* Pm; const float* W; const float* T1; const float* Z;
  float* h; float* hf; float* outp; float* hlast;
  int t, zh, wout;
};
struct FBParams { FBJob j[2]; };
__global__ __launch_bounds__(256,4) void k_fusedB(FBParams pr) {
  __shared__ float Ps[8*32*4];
  FBJob jb = pr.j[blockIdx.y];
  int row0 = blockIdx.x * 8;
  int tid = threadIdx.x;
  int r = tid >> 5, o = tid & 31;
  int row = row0 + r;
  float acc0=0, accR=0, accI=0, acc2=0;
  if (!jb.zh) {
    const size_t psh = (size_t)4*ROWS*HH;
    #pragma unroll
    for (int c = 0; c < 4; ++c) {
      size_t ix = ((size_t)c*ROWS + row)*HH + o;
      Ps[(r*32 + o)*4 + c] = jb.Pm[ix] + jb.Pm[ix + psh];
    }
    __syncthreads();
    #pragma unroll 8
    for (int k = 0; k < 32; ++k) {
      float4 p = *(const float4*)&Ps[(r*32 + k)*4];
      float4 w = *(const float4*)&jb.W[((size_t)(k*32 + o))*4];   // [k][o][c]
      acc0 += p.x*w.x;
      accR += p.y*w.y - p.z*w.z;
      accI += p.y*w.z + p.z*w.y;
      acc2 += p.w*w.w;
    }
  }
  float y0 = 0.25f*(acc0 + 2.f*accR + acc2);
  float y1 = 0.25f*(acc0 - 2.f*accI - acc2);
  float y2 = 0.25f*(acc0 - 2.f*accR + acc2);
  float y3 = 0.25f*(acc0 + 2.f*accI - acc2);
  float4 t1 = *(const float4*)&jb.T1[((size_t)row*HH + o)*4];
  float h0v = tanhf(t1.x + y0);
  float h1v = tanhf(t1.y + y1);
  float h2v = tanhf(t1.z + y2);
  float h3v = tanhf(t1.w + y3);
  float4 z = *(const float4*)&jb.Z[((size_t)row*HH + o)*4];
  float4 hp = make_float4(0,0,0,0);
  if (!jb.zh) hp = *(const float4*)&jb.h[((size_t)row*HH + o)*4];
  float n0v = z.x*hp.x + (1.f-z.x)*h0v;
  float n1v = z.y*hp.y + (1.f-z.y)*h1v;
  float n2v = z.z*hp.z + (1.f-z.z)*h2v;
  float n3v = z.w*hp.w + (1.f-z.w)*h3v;
  *(float4*)&jb.h[((size_t)row*HH + o)*4] = make_float4(n0v,n1v,n2v,n3v);
  size_t hb = (size_t)row*HH + o, cs = (size_t)ROWS*HH;
  jb.hf[hb]      = n0v+n1v+n2v+n3v;
  jb.hf[hb+cs]   = n0v-n2v;
  jb.hf[hb+2*cs] = n3v-n1v;
  jb.hf[hb+3*cs] = n0v-n1v+n2v-n3v;
  int n = row >> 5, b = row & 31;
  if (jb.wout) {
    float* dst = jb.outp + (((size_t)b*TT + jb.t)*NN + n)*(HH*4) + o*4;
    *(float4*)dst = make_float4(n0v,n1v,n2v,n3v);
  }
  if (jb.hlast) {
    float* dst = jb.hlast + ((size_t)(b*NN + n))*(HH*4) + o*4;
    *(float4*)dst = make_float4(n0v,n1v,n2v,n3v);
  }
}

extern "C" void kernel_launch(void* const* d_in, const int* in_sizes, int n_in,
                              void* d_out, int out_size, void* d_ws, size_t ws_size,
                              hipStream_t stream) {
  const float* inp  = (const float*)d_in[0];
  const float* U    = (const float*)d_in[1];
  const float* Wxz0 = (const float*)d_in[2];
  const float* Wxr0 = (const float*)d_in[3];
  const float* Wxh0 = (const float*)d_in[4];
  const float* Whz0 = (const float*)d_in[5];
  const float* Whr0 = (const float*)d_in[6];
  const float* B0   = (const float*)d_in[7];
  const float* Wxz1 = (const float*)d_in[8];
  const float* Wxr1 = (const float*)d_in[9];
  const float* Wxh1 = (const float*)d_in[10];
  const float* Whz1 = (const float*)d_in[11];
  const float* Whr1 = (const float*)d_in[12];
  const float* B1   = (const float*)d_in[13];
  float* out = (float*)d_out;

  float* ws = (float*)d_ws;
  float* ADJF = ws;  ws += SZ_ADJF;
  float* WA0  = ws;  ws += SZ_WA0;
  float* WA1  = ws;  ws += SZ_WA1;
  float* WB0  = ws;  ws += SZ_WB;
  float* WB1  = ws;  ws += SZ_WB;
  float* H0   = ws;  ws += SZ_STATE;
  float* H1   = ws;  ws += SZ_STATE;
  float* H0F  = ws;  ws += SZ_STATE;
  float* H1F  = ws;  ws += SZ_STATE;
  float* PIN  = ws;  ws += 2*SZ_PIN;
  float* PH0  = ws;  ws += 2*SZ_STATE;
  float* PH1  = ws;  ws += 2*SZ_STATE;
  float* PM0  = ws;  ws += 2*SZ_STATE;
  float* PM1  = ws;  ws += 2*SZ_STATE;
  float* M0F  = ws;  ws += SZ_STATE;
  float* M1F  = ws;  ws += SZ_STATE;
  float* Z0   = ws;  ws += SZ_STATE;
  float* Z1   = ws;  ws += SZ_STATE;
  float* T10  = ws;  ws += SZ_STATE;
  float* T11  = ws;  ws += SZ_STATE;

  k_adj<<<NN, 256, 0, stream>>>(U, ADJF);
  k_wts<<<(SZ_WA0+SZ_WA1+2*SZ_WB+255)/256, 256, 0, stream>>>(
      Wxz0,Wxr0,Wxh0,Whz0,Whr0,Wxz1,Wxr1,Wxh1,Whz1,Whr1,WA0,WA1,WB0,WB1);

  // ---- t = 0 (zero hidden) ----
  {
    AggParams p; p.X0=nullptr; p.P0=PIN; p.ncol0=NCIN;
    p.X1=nullptr; p.P1=nullptr; p.ncol1=0; p.X2=nullptr; p.P2=nullptr; p.ncol2=0;
    p.base1=0; p.base2=0; p.njobs=1; p.rawt=0; p.nb=80;
    k_agg<<<160, 256, 0, stream>>>(p, ADJF, inp);
  }
  {
    FAParams p;
    p.j[0] = FAJob{PIN, nullptr, WA0, B0, nullptr, Z0, T10, M0F, 1};
    p.j[1] = p.j[0];
    k_fusedA_L0<<<dim3(600,1), 256, 0, stream>>>(p);
  }
  {
    FBParams p;
    p.j[0] = FBJob{nullptr, WB0, T10, Z0, H0, H0F, nullptr, nullptr, 0, 1, 0};
    p.j[1] = p.j[0];
    k_fusedB<<<dim3(600,1), 256, 0, stream>>>(p);
  }
  {
    AggParams p; p.X0=H0F; p.P0=PH0; p.ncol0=NCH;
    p.X1=nullptr; p.P1=nullptr; p.ncol1=0; p.X2=nullptr; p.P2=nullptr; p.ncol2=0;
    p.base1=0; p.base2=0; p.njobs=1; p.rawt=-1; p.nb=160;
    k_agg<<<320, 256, 0, stream>>>(p, ADJF, inp);
  }
  {
    FAParams p;
    p.j[0] = FAJob{PH0, nullptr, WA1, B1, nullptr, Z1, T11, M1F, 1};
    p.j[1] = p.j[0];
    k_fusedA_L1<<<dim3(600,1), 256, 0, stream>>>(p);
  }
  {
    FBParams p;
    p.j[0] = FBJob{nullptr, WB1, T11, Z1, H1, H1F, out, nullptr, 0, 1, 1};
    p.j[1] = p.j[0];
    k_fusedB<<<dim3(600,1), 256, 0, stream>>>(p);
  }

  // ---- t = 1..7 ----
  float* hlast0 = out + (size_t)BB*TT*NN*HH*4;
  float* hlast1 = hlast0 + (size_t)BB*NN*HH*4;
  for (int t = 1; t < TT; ++t) {
    {
      AggParams p;
      p.X0=nullptr; p.P0=PIN; p.ncol0=NCIN;
      p.X1=H0F; p.P1=PH0; p.ncol1=NCH;
      p.X2=H1F; p.P2=PH1; p.ncol2=NCH;
      p.base1=80; p.base2=240; p.njobs=3; p.rawt=t; p.nb=400;
      k_agg<<<800, 256, 0, stream>>>(p, ADJF, inp);
    }
    {
      FAParams p;
      p.j[0] = FAJob{PIN, PH0, WA0, B0, H0, Z0, T10, M0F, 0};
      p.j[1] = FAJob{PH0, PH1, WA1, B1, H1, Z1, T11, M1F, 0};
      k_fusedA_both<<<dim3(600,2), 256, 0, stream>>>(p);
    }
    {
      AggParams p;
      p.X0=M0F; p.P0=PM0; p.ncol0=NCH;
      p.X1=M1F; p.P1=PM1; p.ncol1=NCH;
      p.X2=nullptr; p.P2=nullptr; p.ncol2=0;
      p.base1=160; p.base2=0; p.njobs=2; p.rawt=-1; p.nb=320;
      k_agg<<<640, 256, 0, stream>>>(p, ADJF, inp);
    }
    {
      int last = (t == TT-1);
      FBParams p;
      p.j[0] = FBJob{PM0, WB0, T10, Z0, H0, H0F, nullptr, last ? hlast0 : nullptr, t, 0, 0};
      p.j[1] = FBJob{PM1, WB1, T11, Z1, H1, H1F, out,     last ? hlast1 : nullptr, t, 0, 1};
      k_fusedB<<<dim3(600,2), 256, 0, stream>>>(p);
    }
  }
}

// Round 4
// 846.236 us; speedup vs baseline: 2.0344x; 1.0452x over previous
//
#include <hip/hip_runtime.h>
#include <math.h>

// Problem constants
#define NN 150   // nodes
#define BB 32    // batch
#define TT 8     // time
#define FF 16    // input features
#define HH 32    // hidden
#define ROWS (NN*BB)     // 4800 (row index = n*32 + b)
#define NCIN (BB*FF)     // 512
#define NCH  (BB*HH)     // 1024
#define ADJ_LD 160       // padded adjacency row stride (zero-filled 150..159)
#define KPAD 68          // Ps k-stride in fusedA

// workspace sizes (floats)
#define SZ_ADJF (4*NN*ADJ_LD)
#define SZ_WA0  (4*48*32*4)   // packed [c][48][32][4]
#define SZ_WA1  (4*64*32*4)   // packed [c][64][32][4]
#define SZ_WB   (32*32*4)     // packed [k][o][c]
#define SZ_STATE (ROWS*HH*4)
#define SZ_PIN  (4*NN*NCIN)

__device__ __forceinline__ float sigmoidf_(float x){ return 1.f/(1.f+expf(-x)); }

__device__ __forceinline__ float comp_of4(float x0, float x1, float x2, float x3, int c) {
  return c==0 ? (x0+x1+x2+x3) : c==1 ? (x0-x2) : c==2 ? (x3-x1) : (x0-x1+x2-x3);
}

// Fourier comps of a real length-4 tube: c0, c1re, c1im, c2 (face3 = conj(face1))
// ifft: y0=(c0+2c1re+c2)/4; y1=(c0-2c1im-c2)/4; y2=(c0-2c1re+c2)/4; y3=(c0+2c1im-c2)/4

// ---------------- adjacency: softmax(relu(ifft(Uf Uf^T))) then comps (padded LD=160) ----------------
__global__ __launch_bounds__(256) void k_adj(const float* __restrict__ U, float* __restrict__ adjF) {
  __shared__ float Ufl[NN*16*4];
  __shared__ float Arow[NN*4];
  __shared__ float red[256];
  __shared__ float mxs[4], isms[4];
  int n = blockIdx.x, tid = threadIdx.x;
  for (int idx = tid; idx < NN*16; idx += 256) {
    const float* s = U + (size_t)idx*4;
    float x0=s[0], x1=s[1], x2=s[2], x3=s[3];
    Ufl[idx*4+0] = x0+x1+x2+x3;
    Ufl[idx*4+1] = x0-x2;
    Ufl[idx*4+2] = x3-x1;
    Ufl[idx*4+3] = x0-x1+x2-x3;
  }
  __syncthreads();
  if (tid < NN) {
    int m = tid;
    float a0=0, ar=0, ai=0, a2=0;
    #pragma unroll
    for (int e = 0; e < 16; ++e) {
      const float* un = &Ufl[(n*16+e)*4];
      const float* um = &Ufl[(m*16+e)*4];
      a0 += un[0]*um[0];
      ar += un[1]*um[1] - un[2]*um[2];
      ai += un[1]*um[2] + un[2]*um[1];
      a2 += un[3]*um[3];
    }
    float r0 = 0.25f*(a0 + 2.f*ar + a2);
    float r1 = 0.25f*(a0 - 2.f*ai - a2);
    float r2 = 0.25f*(a0 - 2.f*ar + a2);
    float r3 = 0.25f*(a0 + 2.f*ai - a2);
    Arow[m*4+0] = fmaxf(r0, 0.f);
    Arow[m*4+1] = fmaxf(r1, 0.f);
    Arow[m*4+2] = fmaxf(r2, 0.f);
    Arow[m*4+3] = fmaxf(r3, 0.f);
  }
  __syncthreads();
  for (int r = 0; r < 4; ++r) {
    float v = (tid < NN) ? Arow[tid*4+r] : -1e30f;
    red[tid] = v; __syncthreads();
    for (int s = 128; s > 0; s >>= 1) { if (tid < s) red[tid] = fmaxf(red[tid], red[tid+s]); __syncthreads(); }
    if (tid == 0) mxs[r] = red[0];
    __syncthreads();
    float e = (tid < NN) ? expf(Arow[tid*4+r] - mxs[r]) : 0.f;
    red[tid] = e; __syncthreads();
    for (int s = 128; s > 0; s >>= 1) { if (tid < s) red[tid] += red[tid+s]; __syncthreads(); }
    if (tid == 0) isms[r] = 1.f / red[0];
    __syncthreads();
    if (tid < NN) Arow[tid*4+r] = e * isms[r];
    __syncthreads();
  }
  if (tid < NN) {
    int m = tid;
    float e0=Arow[m*4+0], e1=Arow[m*4+1], e2=Arow[m*4+2], e3=Arow[m*4+3];
    size_t base = (size_t)n*ADJ_LD + m;
    size_t cs = (size_t)NN*ADJ_LD;
    adjF[base]      = e0+e1+e2+e3;
    adjF[base+cs]   = e0-e2;
    adjF[base+2*cs] = e3-e1;
    adjF[base+3*cs] = e0-e1+e2-e3;
  } else if (tid < ADJ_LD) {
    size_t base = (size_t)n*ADJ_LD + tid;
    size_t cs = (size_t)NN*ADJ_LD;
    adjF[base] = 0.f; adjF[base+cs] = 0.f; adjF[base+2*cs] = 0.f; adjF[base+3*cs] = 0.f;
  }
}

// ---------------- build packed weight comps ----------------
__global__ __launch_bounds__(256) void k_wts(
    const float* __restrict__ Wxz0, const float* __restrict__ Wxr0, const float* __restrict__ Wxh0,
    const float* __restrict__ Whz0, const float* __restrict__ Whr0,
    const float* __restrict__ Wxz1, const float* __restrict__ Wxr1, const float* __restrict__ Wxh1,
    const float* __restrict__ Whz1, const float* __restrict__ Whr1,
    float* __restrict__ WA0p, float* __restrict__ WA1p,
    float* __restrict__ WB0p, float* __restrict__ WB1p) {
  int idx = blockIdx.x*256 + threadIdx.x;
  const float* src = nullptr;
  float* dst; int didx; int c;
  if (idx < SZ_WA0) {               // 24576
    c = idx / 6144;
    int rem = idx % 6144;
    int k = rem >> 7, og = (rem >> 2) & 31, q = rem & 3;
    if (q == 0) src = (k < FF) ? Wxz0 + ((size_t)k*HH + og)*4 : Whz0 + ((size_t)(k-FF)*HH + og)*4;
    else if (q == 1) src = (k < FF) ? Wxr0 + ((size_t)k*HH + og)*4 : Whr0 + ((size_t)(k-FF)*HH + og)*4;
    else if (q == 2 && k < FF) src = Wxh0 + ((size_t)k*HH + og)*4;
    dst = WA0p; didx = idx;
  } else if (idx < SZ_WA0 + SZ_WA1) {  // +32768
    int id = idx - SZ_WA0;
    c = id >> 13;
    int rem = id & 8191;
    int k = rem >> 7, og = (rem >> 2) & 31, q = rem & 3;
    if (q == 0) src = (k < HH) ? Wxz1 + ((size_t)k*HH + og)*4 : Whz1 + ((size_t)(k-HH)*HH + og)*4;
    else if (q == 1) src = (k < HH) ? Wxr1 + ((size_t)k*HH + og)*4 : Whr1 + ((size_t)(k-HH)*HH + og)*4;
    else if (q == 2 && k < HH) src = Wxh1 + ((size_t)k*HH + og)*4;
    dst = WA1p; didx = id;
  } else if (idx < SZ_WA0 + SZ_WA1 + SZ_WB) {
    int id = idx - (SZ_WA0 + SZ_WA1);
    int k = id >> 7, o = (id >> 2) & 31;
    c = id & 3;
    src = Whr0 + ((size_t)k*HH + o)*4;
    dst = WB0p; didx = id;
  } else if (idx < SZ_WA0 + SZ_WA1 + 2*SZ_WB) {
    int id = idx - (SZ_WA0 + SZ_WA1 + SZ_WB);
    int k = id >> 7, o = (id >> 2) & 31;
    c = id & 3;
    src = Whr1 + ((size_t)k*HH + o)*4;
    dst = WB1p; didx = id;
  } else return;
  float v0=0,v1=0,v2=0,v3=0;
  if (src) { v0=src[0]; v1=src[1]; v2=src[2]; v3=src[3]; }
  dst[didx] = comp_of4(v0,v1,v2,v3,c);
}

// ---------------- facewise aggregation with split-K and register prefetch ----------------
struct AggParams {
  const float* X0; const float* X1; const float* X2;
  float* P0; float* P1; float* P2;
  int ncol0, ncol1, ncol2;
  int base1, base2, njobs, rawt, nb;   // nb = blocks per K-part; grid = 2*nb
};
__global__ __launch_bounds__(256,4) void k_agg(AggParams pr, const float* __restrict__ adjF,
                                               const float* __restrict__ inp) {
  __shared__ float As[4*32*37];   // [c][kk][i] stride 37
  __shared__ float Xs[4*32*36];   // [c][kk][col] stride 36
  int bid = blockIdx.x;
  int part = (bid >= pr.nb) ? 1 : 0;
  if (part) bid -= pr.nb;
  const float* X; float* P; int ncol; int tile; bool raw = false;
  if (pr.njobs >= 3 && bid >= pr.base2) { X = pr.X2; P = pr.P2; ncol = pr.ncol2; tile = bid - pr.base2; }
  else if (pr.njobs >= 2 && bid >= pr.base1) { X = pr.X1; P = pr.P1; ncol = pr.ncol1; tile = bid - pr.base1; }
  else { X = pr.X0; P = pr.P0; ncol = pr.ncol0; tile = bid; raw = (pr.rawt >= 0); }
  P += (size_t)part * 4 * NN * ncol;
  int kbeg = part ? 96 : 0;
  int kend = part ? NN : 96;
  int n0 = (tile % 5) * 32;
  int col0 = (tile / 5) * 32;
  int tid = threadIdx.x;
  int ti = tid & 31, tj = tid >> 5;
  int j0 = tj * 4;
  float a0[4]={}, aR[4]={}, aI[4]={}, a2v[4]={};

  float4 pa[4];
  float4 px[4];

  #define LOAD_A(K0)                                                         \
    _Pragma("unroll")                                                        \
    for (int u = 0; u < 4; ++u) {                                            \
      int e = tid + u*256;                                                   \
      int c = e >> 8, rem = e & 255, i = rem >> 3, kq = rem & 7;             \
      int nn_ = n0 + i;                                                      \
      pa[u] = make_float4(0,0,0,0);                                          \
      if (nn_ < NN) pa[u] = *(const float4*)(adjF + ((size_t)c*NN + nn_)*ADJ_LD + (K0) + kq*4); \
    }
  #define STORE_A()                                                          \
    _Pragma("unroll")                                                        \
    for (int u = 0; u < 4; ++u) {                                            \
      int e = tid + u*256;                                                   \
      int c = e >> 8, rem = e & 255, i = rem >> 3, kq = rem & 7;             \
      As[(c*32 + kq*4+0)*37 + i] = pa[u].x;                                  \
      As[(c*32 + kq*4+1)*37 + i] = pa[u].y;                                  \
      As[(c*32 + kq*4+2)*37 + i] = pa[u].z;                                  \
      As[(c*32 + kq*4+3)*37 + i] = pa[u].w;                                  \
    }
  #define LOAD_X(K0)                                                         \
    if (raw) {                                                               \
      int q = tid & 7, kk = tid >> 3;                                        \
      int mm = (K0) + kk;                                                    \
      int col = col0 + q*4;                                                  \
      int b = col >> 4, f = col & 15;                                        \
      px[0]=px[1]=px[2]=px[3]=make_float4(0,0,0,0);                          \
      if (mm < NN) {                                                         \
        const float* s = inp + (((size_t)(b*TT + pr.rawt)*NN + mm)*FF + f)*4;\
        px[0] = *(const float4*)(s+0);                                       \
        px[1] = *(const float4*)(s+4);                                       \
        px[2] = *(const float4*)(s+8);                                       \
        px[3] = *(const float4*)(s+12);                                      \
      }                                                                      \
    } else {                                                                 \
      _Pragma("unroll")                                                      \
      for (int u = 0; u < 4; ++u) {                                          \
        int e = tid + u*256;                                                 \
        int c = e >> 8, rem = e & 255, kk = rem >> 3, q = rem & 7;           \
        int mm = (K0) + kk;                                                  \
        px[u] = make_float4(0,0,0,0);                                        \
        if (mm < NN) px[u] = *(const float4*)(X + ((size_t)c*NN + mm)*ncol + col0 + q*4); \
      }                                                                      \
    }
  #define STORE_X()                                                          \
    if (raw) {                                                               \
      int q = tid & 7, kk = tid >> 3;                                        \
      float4 r0 = px[0], r1 = px[1], r2 = px[2], r3 = px[3];                 \
      float4 w;                                                              \
      w = make_float4(r0.x+r0.y+r0.z+r0.w, r1.x+r1.y+r1.z+r1.w, r2.x+r2.y+r2.z+r2.w, r3.x+r3.y+r3.z+r3.w); \
      *(float4*)&Xs[(0*32+kk)*36 + q*4] = w;                                 \
      w = make_float4(r0.x-r0.z, r1.x-r1.z, r2.x-r2.z, r3.x-r3.z);           \
      *(float4*)&Xs[(1*32+kk)*36 + q*4] = w;                                 \
      w = make_float4(r0.w-r0.y, r1.w-r1.y, r2.w-r2.y, r3.w-r3.y);           \
      *(float4*)&Xs[(2*32+kk)*36 + q*4] = w;                                 \
      w = make_float4(r0.x-r0.y+r0.z-r0.w, r1.x-r1.y+r1.z-r1.w, r2.x-r2.y+r2.z-r2.w, r3.x-r3.y+r3.z-r3.w); \
      *(float4*)&Xs[(3*32+kk)*36 + q*4] = w;                                 \
    } else {                                                                 \
      _Pragma("unroll")                                                      \
      for (int u = 0; u < 4; ++u) {                                          \
        int e = tid + u*256;                                                 \
        int c = e >> 8, rem = e & 255, kk = rem >> 3, q = rem & 7;           \
        *(float4*)&Xs[(c*32+kk)*36 + q*4] = px[u];                           \
      }                                                                      \
    }

  LOAD_A(kbeg)
  LOAD_X(kbeg)
  for (int k0 = kbeg; k0 < kend; k0 += 32) {
    STORE_A()
    STORE_X()
    __syncthreads();
    int k0n = k0 + 32;
    if (k0n < kend) {
      LOAD_A(k0n)
      LOAD_X(k0n)
    }
    #pragma unroll 4
    for (int k = 0; k < 32; ++k) {
      float A0 = As[(0*32+k)*37 + ti];
      float A1 = As[(1*32+k)*37 + ti];
      float A2 = As[(2*32+k)*37 + ti];
      float A3 = As[(3*32+k)*37 + ti];
      float4 x0 = *(float4*)&Xs[(0*32+k)*36 + j0];
      float4 x1 = *(float4*)&Xs[(1*32+k)*36 + j0];
      float4 x2 = *(float4*)&Xs[(2*32+k)*36 + j0];
      float4 x3 = *(float4*)&Xs[(3*32+k)*36 + j0];
      float X0v[4]={x0.x,x0.y,x0.z,x0.w}, X1v[4]={x1.x,x1.y,x1.z,x1.w};
      float X2v[4]={x2.x,x2.y,x2.z,x2.w}, X3v[4]={x3.x,x3.y,x3.z,x3.w};
      #pragma unroll
      for (int j = 0; j < 4; ++j) {
        a0[j] += A0*X0v[j];
        aR[j] += A1*X1v[j] - A2*X2v[j];
        aI[j] += A1*X2v[j] + A2*X1v[j];
        a2v[j] += A3*X3v[j];
      }
    }
    __syncthreads();
  }
  int nn_ = n0 + ti;
  if (nn_ < NN) {
    size_t cs = (size_t)NN*ncol;
    size_t rb = (size_t)nn_*ncol + col0 + j0;
    *(float4*)&P[rb]      = make_float4(a0[0],a0[1],a0[2],a0[3]);
    *(float4*)&P[rb+cs]   = make_float4(aR[0],aR[1],aR[2],aR[3]);
    *(float4*)&P[rb+2*cs] = make_float4(aI[0],aI[1],aI[2],aI[3]);
    *(float4*)&P[rb+3*cs] = make_float4(a2v[0],a2v[1],a2v[2],a2v[3]);
  }
}

// ---------------- phase A: transform + gates -> Z, T1, Mf ----------------
// 16 rows/block; W staged in LDS in 16-k chunks (32 KB); Ps [r][c][KPAD] (17 KB).
struct FAJob {
  const float* Px;   // partial pair: [2][c][ROWS][Kx]
  const float* Ph;   // partial pair: [2][c][ROWS][32]
  const float* W;    // packed [c][Ktot][32][4]
  const float* bias;
  const float* hprev;
  float* Z; float* T1; float* Mf;
  int zh;
};
struct FAParams { FAJob j[2]; };

template<int KTOT, int KX>
__device__ __forceinline__ void fusedA_body(const FAJob& jb, float* Ps, float* Ws) {
  const int row0 = blockIdx.x * 16;
  const int tid = threadIdx.x;
  const int og = tid & 31;
  const int rg = tid >> 5;          // 0..7
  const int r0 = rg*2, r1 = rg*2 + 1;
  const size_t psx = (size_t)4*ROWS*KX;
  const size_t psh = (size_t)4*ROWS*HH;
  constexpr int K4 = KTOT/4;
  // stage Ps (summing split-K partials)
  for (int e = tid; e < 16*4*K4; e += 256) {
    int k4 = e % K4; int c = (e / K4) & 3; int r = e / (K4*4);
    int k = k4*4;
    int row = row0 + r;
    float4 v;
    if (k < KX) {
      const float* a = &jb.Px[((size_t)c*ROWS + row)*KX + k];
      float4 va = *(const float4*)a;
      float4 vb = *(const float4*)(a + psx);
      v = make_float4(va.x+vb.x, va.y+vb.y, va.z+vb.z, va.w+vb.w);
    } else if (jb.zh) {
      v = make_float4(0,0,0,0);
    } else {
      const float* a = &jb.Ph[((size_t)c*ROWS + row)*HH + (k - KX)];
      float4 va = *(const float4*)a;
      float4 vb = *(const float4*)(a + psh);
      v = make_float4(va.x+vb.x, va.y+vb.y, va.z+vb.z, va.w+vb.w);
    }
    *(float4*)&Ps[(r*4 + c)*KPAD + k] = v;
  }
  float acc0[2][3]={{0,0,0},{0,0,0}}, accR[2][3]={{0,0,0},{0,0,0}};
  float accI[2][3]={{0,0,0},{0,0,0}}, acc2[2][3]={{0,0,0},{0,0,0}};
  constexpr int NCHK = KTOT/16;
  const float4* Wg = (const float4*)jb.W;       // [c][KTOT][32] float4s
  for (int cc = 0; cc < NCHK; ++cc) {
    __syncthreads();   // Ws reuse guard (first iter also covers Ps staging)
    #pragma unroll
    for (int u = 0; u < 8; ++u) {
      int f = tid + u*256;                       // 2048 float4s
      int c = f >> 9, rem = f & 511;
      float4 v = Wg[((size_t)c*KTOT + cc*16)*32 + rem];
      *(float4*)&Ws[((size_t)c*512 + rem)*4] = v;
    }
    __syncthreads();
    #pragma unroll 4
    for (int kk = 0; kk < 16; ++kk) {
      int k = cc*16 + kk;
      float p0a = Ps[(r0*4+0)*KPAD + k];
      float p1a = Ps[(r0*4+1)*KPAD + k];
      float p2a = Ps[(r0*4+2)*KPAD + k];
      float p3a = Ps[(r0*4+3)*KPAD + k];
      float p0b = Ps[(r1*4+0)*KPAD + k];
      float p1b = Ps[(r1*4+1)*KPAD + k];
      float p2b = Ps[(r1*4+2)*KPAD + k];
      float p3b = Ps[(r1*4+3)*KPAD + k];
      float4 w0 = *(float4*)&Ws[((0*16+kk)*32+og)*4];
      float4 w1 = *(float4*)&Ws[((1*16+kk)*32+og)*4];
      float4 w2 = *(float4*)&Ws[((2*16+kk)*32+og)*4];
      float4 w3 = *(float4*)&Ws[((3*16+kk)*32+og)*4];
      float W0v[3]={w0.x,w0.y,w0.z}, W1v[3]={w1.x,w1.y,w1.z};
      float W2v[3]={w2.x,w2.y,w2.z}, W3v[3]={w3.x,w3.y,w3.z};
      #pragma unroll
      for (int q = 0; q < 3; ++q) {
        acc0[0][q] += p0a*W0v[q];
        acc0[1][q] += p0b*W0v[q];
        accR[0][q] += p1a*W1v[q] - p2a*W2v[q];
        accR[1][q] += p1b*W1v[q] - p2b*W2v[q];
        accI[0][q] += p1a*W2v[q] + p2a*W1v[q];
        accI[1][q] += p1b*W2v[q] + p2b*W1v[q];
        acc2[0][q] += p3a*W3v[q];
        acc2[1][q] += p3b*W3v[q];
      }
    }
  }
  // epilogue (bias depends only on og)
  const float* bz = jb.bias + (0*HH + og)*4;
  const float* br = jb.bias + (1*HH + og)*4;
  const float* bh = jb.bias + (2*HH + og)*4;
  float bzv[4] = {bz[0],bz[1],bz[2],bz[3]};
  float brv[4] = {br[0],br[1],br[2],br[3]};
  float bhv[4] = {bh[0],bh[1],bh[2],bh[3]};
  #pragma unroll
  for (int rr = 0; rr < 2; ++rr) {
    int row = row0 + rg*2 + rr;
    float ys[3][4];
    #pragma unroll
    for (int q = 0; q < 3; ++q) {
      float Y0 = acc0[rr][q], Yr = accR[rr][q], Yi = accI[rr][q], Y2 = acc2[rr][q];
      ys[q][0] = 0.25f*(Y0 + 2.f*Yr + Y2);
      ys[q][1] = 0.25f*(Y0 - 2.f*Yi - Y2);
      ys[q][2] = 0.25f*(Y0 - 2.f*Yr + Y2);
      ys[q][3] = 0.25f*(Y0 + 2.f*Yi - Y2);
    }
    float4 z = make_float4(sigmoidf_(ys[0][0]+bzv[0]), sigmoidf_(ys[0][1]+bzv[1]),
                           sigmoidf_(ys[0][2]+bzv[2]), sigmoidf_(ys[0][3]+bzv[3]));
    *(float4*)&jb.Z[((size_t)row*HH + og)*4] = z;
    float4 hp = make_float4(0,0,0,0);
    if (!jb.zh) hp = *(const float4*)&jb.hprev[((size_t)row*HH + og)*4];
    float m0 = sigmoidf_(ys[1][0]+brv[0]) * hp.x;
    float m1 = sigmoidf_(ys[1][1]+brv[1]) * hp.y;
    float m2 = sigmoidf_(ys[1][2]+brv[2]) * hp.z;
    float m3 = sigmoidf_(ys[1][3]+brv[3]) * hp.w;
    size_t mb = (size_t)row*HH + og;
    size_t cs = (size_t)ROWS*HH;
    jb.Mf[mb]      = m0+m1+m2+m3;
    jb.Mf[mb+cs]   = m0-m2;
    jb.Mf[mb+2*cs] = m3-m1;
    jb.Mf[mb+3*cs] = m0-m1+m2-m3;
    float4 tv = make_float4(ys[2][0]+bhv[0], ys[2][1]+bhv[1], ys[2][2]+bhv[2], ys[2][3]+bhv[3]);
    *(float4*)&jb.T1[((size_t)row*HH + og)*4] = tv;
  }
}

__global__ __launch_bounds__(256,3) void k_fusedA_both(FAParams pr) {
  __shared__ float Ps[16*4*KPAD];
  __shared__ float Ws[8192];
  if (blockIdx.y == 0) fusedA_body<48,16>(pr.j[0], Ps, Ws);
  else                 fusedA_body<64,32>(pr.j[1], Ps, Ws);
}
__global__ __launch_bounds__(256,3) void k_fusedA_L0(FAParams pr) {
  __shared__ float Ps[16*4*KPAD];
  __shared__ float Ws[8192];
  fusedA_body<48,16>(pr.j[0], Ps, Ws);
}
__global__ __launch_bounds__(256,3) void k_fusedA_L1(FAParams pr) {
  __shared__ float Ps[16*4*KPAD];
  __shared__ float Ws[8192];
  fusedA_body<64,32>(pr.j[1], Ps, Ws);
}

// ---------------- phase B: Ht=tanh(T1+ifft(Pm.W)); Hnew=Z*Hprev+(1-Z)*Ht ----------------
// 16 rows/block; W (16 KB) fully staged in LDS; 2 rows per thread.
struct FBJob {
  const float* Pm; const float* W; const float* T1; const float* Z;
  float* h; float* hf; float* outp; float* hlast;
  int t, zh, wout;
};
struct FBParams { FBJob j[2]; };
__global__ __launch_bounds__(256,4) void k_fusedB(FBParams pr) {
  __shared__ float Ps[16*32*4];   // [r][k][c]
  __shared__ float Ws[32*32*4];   // [k][o][c]
  FBJob jb = pr.j[blockIdx.y];
  int row0 = blockIdx.x * 16;
  int tid = threadIdx.x;
  int rg = tid >> 5, o = tid & 31;
  int r0 = rg*2, r1 = r0 + 1;
  float acc0[2]={0,0}, accR[2]={0,0}, accI[2]={0,0}, acc2[2]={0,0};
  if (!jb.zh) {
    #pragma unroll
    for (int u = 0; u < 4; ++u) {
      int f = tid + u*256;
      ((float4*)Ws)[f] = ((const float4*)jb.W)[f];
    }
    const size_t psh = (size_t)4*ROWS*HH;
    #pragma unroll
    for (int u = 0; u < 2; ++u) {
      int e = tid + u*256;          // 512 (r,k) entries
      int r = e >> 5, k = e & 31;
      int row = row0 + r;
      float4 v;
      float* vv = (float*)&v;
      #pragma unroll
      for (int c = 0; c < 4; ++c) {
        size_t ix = ((size_t)c*ROWS + row)*HH + k;
        vv[c] = jb.Pm[ix] + jb.Pm[ix + psh];
      }
      *(float4*)&Ps[(r*32 + k)*4] = v;
    }
    __syncthreads();
    #pragma unroll 8
    for (int k = 0; k < 32; ++k) {
      float4 pA = *(const float4*)&Ps[(r0*32 + k)*4];
      float4 pB = *(const float4*)&Ps[(r1*32 + k)*4];
      float4 w  = *(const float4*)&Ws[(k*32 + o)*4];
      acc0[0] += pA.x*w.x;  acc0[1] += pB.x*w.x;
      accR[0] += pA.y*w.y - pA.z*w.z;  accR[1] += pB.y*w.y - pB.z*w.z;
      accI[0] += pA.y*w.z + pA.z*w.y;  accI[1] += pB.y*w.z + pB.z*w.y;
      acc2[0] += pA.w*w.w;  acc2[1] += pB.w*w.w;
    }
  }
  #pragma unroll
  for (int rr = 0; rr < 2; ++rr) {
    int row = row0 + rg*2 + rr;
    float y0 = 0.25f*(acc0[rr] + 2.f*accR[rr] + acc2[rr]);
    float y1 = 0.25f*(acc0[rr] - 2.f*accI[rr] - acc2[rr]);
    float y2 = 0.25f*(acc0[rr] - 2.f*accR[rr] + acc2[rr]);
    float y3 = 0.25f*(acc0[rr] + 2.f*accI[rr] - acc2[rr]);
    float4 t1 = *(const float4*)&jb.T1[((size_t)row*HH + o)*4];
    float h0v = tanhf(t1.x + y0);
    float h1v = tanhf(t1.y + y1);
    float h2v = tanhf(t1.z + y2);
    float h3v = tanhf(t1.w + y3);
    float4 z = *(const float4*)&jb.Z[((size_t)row*HH + o)*4];
    float4 hp = make_float4(0,0,0,0);
    if (!jb.zh) hp = *(const float4*)&jb.h[((size_t)row*HH + o)*4];
    float n0v = z.x*hp.x + (1.f-z.x)*h0v;
    float n1v = z.y*hp.y + (1.f-z.y)*h1v;
    float n2v = z.z*hp.z + (1.f-z.z)*h2v;
    float n3v = z.w*hp.w + (1.f-z.w)*h3v;
    *(float4*)&jb.h[((size_t)row*HH + o)*4] = make_float4(n0v,n1v,n2v,n3v);
    size_t hb = (size_t)row*HH + o, cs = (size_t)ROWS*HH;
    jb.hf[hb]      = n0v+n1v+n2v+n3v;
    jb.hf[hb+cs]   = n0v-n2v;
    jb.hf[hb+2*cs] = n3v-n1v;
    jb.hf[hb+3*cs] = n0v-n1v+n2v-n3v;
    int n = row >> 5, b = row & 31;
    if (jb.wout) {
      float* dst = jb.outp + (((size_t)b*TT + jb.t)*NN + n)*(HH*4) + o*4;
      *(float4*)dst = make_float4(n0v,n1v,n2v,n3v);
    }
    if (jb.hlast) {
      float* dst = jb.hlast + ((size_t)(b*NN + n))*(HH*4) + o*4;
      *(float4*)dst = make_float4(n0v,n1v,n2v,n3v);
    }
  }
}

extern "C" void kernel_launch(void* const* d_in, const int* in_sizes, int n_in,
                              void* d_out, int out_size, void* d_ws, size_t ws_size,
                              hipStream_t stream) {
  const float* inp  = (const float*)d_in[0];
  const float* U    = (const float*)d_in[1];
  const float* Wxz0 = (const float*)d_in[2];
  const float* Wxr0 = (const float*)d_in[3];
  const float* Wxh0 = (const float*)d_in[4];
  const float* Whz0 = (const float*)d_in[5];
  const float* Whr0 = (const float*)d_in[6];
  const float* B0   = (const float*)d_in[7];
  const float* Wxz1 = (const float*)d_in[8];
  const float* Wxr1 = (const float*)d_in[9];
  const float* Wxh1 = (const float*)d_in[10];
  const float* Whz1 = (const float*)d_in[11];
  const float* Whr1 = (const float*)d_in[12];
  const float* B1   = (const float*)d_in[13];
  float* out = (float*)d_out;

  float* ws = (float*)d_ws;
  float* ADJF = ws;  ws += SZ_ADJF;
  float* WA0  = ws;  ws += SZ_WA0;
  float* WA1  = ws;  ws += SZ_WA1;
  float* WB0  = ws;  ws += SZ_WB;
  float* WB1  = ws;  ws += SZ_WB;
  float* H0   = ws;  ws += SZ_STATE;
  float* H1   = ws;  ws += SZ_STATE;
  float* H0F  = ws;  ws += SZ_STATE;
  float* H1F  = ws;  ws += SZ_STATE;
  float* PIN  = ws;  ws += 2*SZ_PIN;
  float* PH0  = ws;  ws += 2*SZ_STATE;
  float* PH1  = ws;  ws += 2*SZ_STATE;
  float* PM0  = ws;  ws += 2*SZ_STATE;
  float* PM1  = ws;  ws += 2*SZ_STATE;
  float* M0F  = ws;  ws += SZ_STATE;
  float* M1F  = ws;  ws += SZ_STATE;
  float* Z0   = ws;  ws += SZ_STATE;
  float* Z1   = ws;  ws += SZ_STATE;
  float* T10  = ws;  ws += SZ_STATE;
  float* T11  = ws;  ws += SZ_STATE;

  k_adj<<<NN, 256, 0, stream>>>(U, ADJF);
  k_wts<<<(SZ_WA0+SZ_WA1+2*SZ_WB+255)/256, 256, 0, stream>>>(
      Wxz0,Wxr0,Wxh0,Whz0,Whr0,Wxz1,Wxr1,Wxh1,Whz1,Whr1,WA0,WA1,WB0,WB1);

  // ---- t = 0 (zero hidden) ----
  {
    AggParams p; p.X0=nullptr; p.P0=PIN; p.ncol0=NCIN;
    p.X1=nullptr; p.P1=nullptr; p.ncol1=0; p.X2=nullptr; p.P2=nullptr; p.ncol2=0;
    p.base1=0; p.base2=0; p.njobs=1; p.rawt=0; p.nb=80;
    k_agg<<<160, 256, 0, stream>>>(p, ADJF, inp);
  }
  {
    FAParams p;
    p.j[0] = FAJob{PIN, nullptr, WA0, B0, nullptr, Z0, T10, M0F, 1};
    p.j[1] = p.j[0];
    k_fusedA_L0<<<dim3(300,1), 256, 0, stream>>>(p);
  }
  {
    FBParams p;
    p.j[0] = FBJob{nullptr, WB0, T10, Z0, H0, H0F, nullptr, nullptr, 0, 1, 0};
    p.j[1] = p.j[0];
    k_fusedB<<<dim3(300,1), 256, 0, stream>>>(p);
  }
  {
    AggParams p; p.X0=H0F; p.P0=PH0; p.ncol0=NCH;
    p.X1=nullptr; p.P1=nullptr; p.ncol1=0; p.X2=nullptr; p.P2=nullptr; p.ncol2=0;
    p.base1=0; p.base2=0; p.njobs=1; p.rawt=-1; p.nb=160;
    k_agg<<<320, 256, 0, stream>>>(p, ADJF, inp);
  }
  {
    FAParams p;
    p.j[0] = FAJob{PH0, nullptr, WA1, B1, nullptr, Z1, T11, M1F, 1};
    p.j[1] = p.j[0];
    k_fusedA_L1<<<dim3(300,1), 256, 0, stream>>>(p);
  }
  {
    FBParams p;
    p.j[0] = FBJob{nullptr, WB1, T11, Z1, H1, H1F, out, nullptr, 0, 1, 1};
    p.j[1] = p.j[0];
    k_fusedB<<<dim3(300,1), 256, 0, stream>>>(p);
  }

  // ---- t = 1..7 ----
  float* hlast0 = out + (size_t)BB*TT*NN*HH*4;
  float* hlast1 = hlast0 + (size_t)BB*NN*HH*4;
  for (int t = 1; t < TT; ++t) {
    {
      AggParams p;
      p.X0=nullptr; p.P0=PIN; p.ncol0=NCIN;
      p.X1=H0F; p.P1=PH0; p.ncol1=NCH;
      p.X2=H1F; p.P2=PH1; p.ncol2=NCH;
      p.base1=80; p.base2=240; p.njobs=3; p.rawt=t; p.nb=400;
      k_agg<<<800, 256, 0, stream>>>(p, ADJF, inp);
    }
    {
      FAParams p;
      p.j[0] = FAJob{PIN, PH0, WA0, B0, H0, Z0, T10, M0F, 0};
      p.j[1] = FAJob{PH0, PH1, WA1, B1, H1, Z1, T11, M1F, 0};
      k_fusedA_both<<<dim3(300,2), 256, 0, stream>>>(p);
    }
    {
      AggParams p;
      p.X0=M0F; p.P0=PM0; p.ncol0=NCH;
      p.X1=M1F; p.P1=PM1; p.ncol1=NCH;
      p.X2=nullptr; p.P2=nullptr; p.ncol2=0;
      p.base1=160; p.base2=0; p.njobs=2; p.rawt=-1; p.nb=320;
      k_agg<<<640, 256, 0, stream>>>(p, ADJF, inp);
    }
    {
      int last = (t == TT-1);
      FBParams p;
      p.j[0] = FBJob{PM0, WB0, T10, Z0, H0, H0F, nullptr, last ? hlast0 : nullptr, t, 0, 0};
      p.j[1] = FBJob{PM1, WB1, T11, Z1, H1, H1F, out,     last ? hlast1 : nullptr, t, 0, 1};
      k_fusedB<<<dim3(300,2), 256, 0, stream>>>(p);
    }
  }
}